// Round 9
// baseline (418.193 us; speedup 1.0000x reference)
//
#include <hip/hip_runtime.h>
#include <hip/hip_bf16.h>
#include <cmath>

typedef __bf16 bf16_t;
typedef __bf16 bf16x4 __attribute__((ext_vector_type(4)));
typedef __bf16 bf16x8 __attribute__((ext_vector_type(8)));
typedef float  f32x4  __attribute__((ext_vector_type(4)));

// ---------------------------------------------------------------------------
// async global->LDS, 16B per lane (LDS dest = wave-uniform base + lane*16)
// ---------------------------------------------------------------------------
__device__ __forceinline__ void gld_lds16(const bf16_t* g, bf16_t* l) {
    __builtin_amdgcn_global_load_lds(
        (const __attribute__((address_space(1))) void*)g,
        (__attribute__((address_space(3))) void*)l,
        16, 0, 0);
}

// LDS bank swizzle for 64B-row planes read at row-stride-64B:
//   physical 16B slot = logical slot ^ ((row>>1)&3)   (involution)
// write side: pre-swizzle the GLOBAL source col; read side: XOR same term.

// ---------------------------------------------------------------------------
// prep: ONE launch for x-cast + 6 weight transposes + qk-bias pack
// ---------------------------------------------------------------------------
struct PrepArgs {
    const float* w[6]; bf16_t* wt[6];
    int K[6], N[6], start[6];
    const float* x; bf16_t* xb; int castStart;   // transpose-region end
    const float* bq; const float* bk; float* bqkv; int biasStart;
};

__global__ __launch_bounds__(256) void prep(PrepArgs pa) {
    __shared__ float tile[32][33];
    const int bid = blockIdx.x, t = threadIdx.x;
    if (bid < pa.castStart) {
        int mi = 0;
#pragma unroll
        for (int i = 1; i < 6; i++) if (bid >= pa.start[i]) mi = i;
        const int tt  = bid - pa.start[mi];
        const int nbx = pa.N[mi] >> 5;
        const int n0 = (tt % nbx) * 32, k0 = (tt / nbx) * 32;
        const float* in = pa.w[mi];
        bf16_t* out = pa.wt[mi];
        const int K = pa.K[mi], N = pa.N[mi];
        const int tx = t & 31, ty = t >> 5;
#pragma unroll
        for (int i = 0; i < 4; i++) {
            int kk = ty + i * 8;
            tile[kk][tx] = in[(size_t)(k0 + kk) * N + n0 + tx];
        }
        __syncthreads();
#pragma unroll
        for (int i = 0; i < 4; i++) {
            int nn = ty + i * 8;
            out[(size_t)(n0 + nn) * K + k0 + tx] = (bf16_t)tile[tx][nn];
        }
    } else if (bid < pa.biasStart) {
        int i = (bid - pa.castStart) * 256 + t;
        f32x4 v = ((const f32x4*)pa.x)[i];
        bf16x4 o;
        o[0] = (bf16_t)v[0]; o[1] = (bf16_t)v[1]; o[2] = (bf16_t)v[2]; o[3] = (bf16_t)v[3];
        ((bf16x4*)pa.xb)[i] = o;
    } else {
#pragma unroll
        for (int j = 0; j < 8; j++) {
            int idx = t * 8 + j;
            pa.bqkv[idx] = idx < 1024 ? pa.bq[idx] : pa.bk[idx - 1024];
        }
    }
}

// ---------------------------------------------------------------------------
// Deep-pipelined 256x256 GEMM: BK=32, 4 LDS buffers, depth-3 counted vmcnt
// + swizzled LDS + setprio.  8 waves, 512 thr.  [R4-proven on FF1]
// ATOMIC=1 (FF2 split-K=4): kh pairs {0,2} and {1,3} atomicAdd f32 into
// Cf + (kh&1)*M*N (zeroed beforehand) -> 4-way split-K with only 2 partial
// buffers; f32 atomic rounding jitter ~1e-7, invisible at 0.05 tolerance.
// ---------------------------------------------------------------------------
template<int BN, int ATOMIC>
__global__ __launch_bounds__(512, 1) void gemm_deep(
    const bf16_t* __restrict__ A, const bf16_t* __restrict__ Bt,
    const float* __restrict__ bias,
    float* __restrict__ Cf, bf16_t* __restrict__ Cb,
    int M, int N, int lda, int Kloc, int relu, int nbn) {
    constexpr int NT = BN / 64;
    constexpr int WN = BN / 4;
    __shared__ __attribute__((aligned(16))) bf16_t As[4][256 * 32];
    __shared__ __attribute__((aligned(16))) bf16_t Bs[4][BN * 32];
    const int tid  = threadIdx.x;            // 0..511
    const int lane = tid & 63;
    const int wave = tid >> 6;               // 0..7
    const int wm = wave >> 2, wn = wave & 3; // 2M x 4N
    const int kh = blockIdx.z;

    const int span  = 8 * nbn;
    const int group = blockIdx.x / span;
    const int rem   = blockIdx.x % span;
    const int bm    = group * 8 + (rem & 7);
    const int bn    = rem >> 3;

    float* Cf_b = Cf ? Cf + (size_t)(ATOMIC ? (kh & 1) : kh) * M * N : nullptr;
    const int koff = kh * Kloc;

    const int srow   = tid >> 2;
    const int slot_s = ((tid & 3) ^ ((tid >> 3) & 3)) * 8;
    const bf16_t* Ag = A  + (size_t)(bm * 256 + srow) * lda + koff + slot_s;
    const bf16_t* Bg = Bt + (size_t)(bn * BN  + srow) * lda + koff + slot_s;

    auto stage = [&](int kk, int buf) {
        gld_lds16(Ag + kk,                       &As[buf][0]        + tid * 8);
        gld_lds16(Ag + (size_t)128 * lda + kk,   &As[buf][128 * 32] + tid * 8);
        gld_lds16(Bg + kk,                       &Bs[buf][0]        + tid * 8);
        if constexpr (BN == 256)
            gld_lds16(Bg + (size_t)128 * lda + kk, &Bs[buf][128 * 32] + tid * 8);
    };

    f32x4 acc[8][NT] = {};
    const int mrow = lane & 15;
    const int qsw  = (((lane >> 4) ^ ((mrow >> 1) & 3))) * 8;

    auto compute = [&](int cur) {
        bf16x8 bfr[NT], af[8];
#pragma unroll
        for (int n = 0; n < NT; n++)
            bfr[n] = *(const bf16x8*)(&Bs[cur][(wn * WN + n * 16 + mrow) * 32 + qsw]);
#pragma unroll
        for (int mt = 0; mt < 8; mt++)
            af[mt] = *(const bf16x8*)(&As[cur][(wm * 128 + mt * 16 + mrow) * 32 + qsw]);
        __builtin_amdgcn_s_setprio(1);
#pragma unroll
        for (int mt = 0; mt < 8; mt++)
#pragma unroll
            for (int n = 0; n < NT; n++)
                acc[mt][n] = __builtin_amdgcn_mfma_f32_16x16x32_bf16(
                    af[mt], bfr[n], acc[mt][n], 0, 0, 0);
        __builtin_amdgcn_s_setprio(0);
    };

    stage(0, 0); stage(32, 1); stage(64, 2);
    const int nst = Kloc >> 5;
    for (int t = 0; t + 3 < nst; ++t) {
        stage((t + 3) * 32, (t + 3) & 3);
        if constexpr (BN == 256) asm volatile("s_waitcnt vmcnt(12)" ::: "memory");
        else                     asm volatile("s_waitcnt vmcnt(9)"  ::: "memory");
        __builtin_amdgcn_s_barrier();
        compute(t & 3);
        asm volatile("s_waitcnt lgkmcnt(0)" ::: "memory");
        __builtin_amdgcn_s_barrier();
    }
    if constexpr (BN == 256) asm volatile("s_waitcnt vmcnt(8)" ::: "memory");
    else                     asm volatile("s_waitcnt vmcnt(6)" ::: "memory");
    __builtin_amdgcn_s_barrier();
    compute((nst - 3) & 3);
    asm volatile("s_waitcnt lgkmcnt(0)" ::: "memory");
    __builtin_amdgcn_s_barrier();
    if constexpr (BN == 256) asm volatile("s_waitcnt vmcnt(4)" ::: "memory");
    else                     asm volatile("s_waitcnt vmcnt(3)" ::: "memory");
    __builtin_amdgcn_s_barrier();
    compute((nst - 2) & 3);
    asm volatile("s_waitcnt lgkmcnt(0)" ::: "memory");
    __builtin_amdgcn_s_barrier();
    asm volatile("s_waitcnt vmcnt(0)" ::: "memory");
    __builtin_amdgcn_s_barrier();
    compute((nst - 1) & 3);

    const int rq = (lane >> 4) * 4;
#pragma unroll
    for (int mt = 0; mt < 8; mt++) {
        int row0 = bm * 256 + wm * 128 + mt * 16 + rq;
#pragma unroll
        for (int n = 0; n < NT; n++) {
            int col = bn * BN + wn * WN + n * 16 + mrow;
            float bvc = (bias && kh == 0) ? bias[col] : 0.f;
#pragma unroll
            for (int r = 0; r < 4; r++) {
                float v = acc[mt][n][r] + bvc;
                if (relu) v = fmaxf(v, 0.f);
                size_t idx = (size_t)(row0 + r) * N + col;
                if constexpr (ATOMIC) {
                    atomicAdd(&Cf_b[idx], v);
                } else {
                    if (Cf_b) Cf_b[idx] = v;
                    if (Cb)   Cb[idx]   = (bf16_t)v;
                }
            }
        }
    }
}

// ---------------------------------------------------------------------------
// 128x256 big-tile GEMM, BK=64, 2-phase dbuf (QK / Wo).  Swizzled LDS.
// ---------------------------------------------------------------------------
template<int BM, int BN>
__global__ __launch_bounds__(512, 2) void gemm_tile(
    const bf16_t* __restrict__ A, const bf16_t* __restrict__ Bt,
    const float* __restrict__ bias,
    float* __restrict__ Cf, bf16_t* __restrict__ Cb,
    int M, int N, int lda, int Kloc, int relu, int nbn) {
    constexpr int MF = BM / 32;
    constexpr int NT = BN / 64;
    constexpr int WM = BM / 2;
    constexpr int WN = BN / 4;
    __shared__ __attribute__((aligned(16))) bf16_t As[2][2][BM * 32];
    __shared__ __attribute__((aligned(16))) bf16_t Bs[2][2][BN * 32];
    const int tid  = threadIdx.x;
    const int lane = tid & 63;
    const int wave = tid >> 6;
    const int wm = wave >> 2, wn = wave & 3;
    const int kh = blockIdx.z;

    const int span  = 8 * nbn;
    const int group = blockIdx.x / span;
    const int rem   = blockIdx.x % span;
    const int bm    = group * 8 + (rem & 7);
    const int bn    = rem >> 3;

    float*  Cf_b = Cf ? Cf + (size_t)kh * M * N : nullptr;
    const int koff = kh * Kloc;

    const int r4 = tid >> 2;
    const int kcs = ((tid & 3) ^ ((tid >> 3) & 3)) * 8;
    const bf16_t* Ag = A  + (size_t)(bm * BM + r4) * lda + koff + kcs;
    const bf16_t* Bg = Bt + (size_t)(bn * BN + r4) * lda + koff + kcs;

    f32x4 acc[MF][NT] = {};
    const int mrow = lane & 15;
    const int qsw  = (((lane >> 4) ^ ((mrow >> 1) & 3))) * 8;

    auto stage = [&](int kk, int buf) {
#pragma unroll
        for (int hh = 0; hh < 2; hh++) {
#pragma unroll
            for (int i = 0; i < BM / 128; i++)
                gld_lds16(Ag + (size_t)(i * 128) * lda + kk + hh * 32,
                          &As[buf][hh][i * 128 * 32] + tid * 8);
#pragma unroll
            for (int i = 0; i < BN / 128; i++)
                gld_lds16(Bg + (size_t)(i * 128) * lda + kk + hh * 32,
                          &Bs[buf][hh][i * 128 * 32] + tid * 8);
        }
    };

    stage(0, 0);
    __syncthreads();

    const int nsteps = Kloc >> 6;
    for (int st = 0; st < nsteps; ++st) {
        const int cur = st & 1;
        if (st + 1 < nsteps) stage((st + 1) << 6, cur ^ 1);

#pragma unroll
        for (int hh = 0; hh < 2; hh++) {
            bf16x8 bfr[NT];
#pragma unroll
            for (int n = 0; n < NT; n++)
                bfr[n] = *(const bf16x8*)(&Bs[cur][hh][(wn * WN + n * 16 + mrow) * 32 + qsw]);
            __builtin_amdgcn_s_setprio(1);
#pragma unroll
            for (int mt = 0; mt < MF; mt++) {
                bf16x8 af = *(const bf16x8*)(&As[cur][hh][(wm * WM + mt * 16 + mrow) * 32 + qsw]);
#pragma unroll
                for (int n = 0; n < NT; n++)
                    acc[mt][n] = __builtin_amdgcn_mfma_f32_16x16x32_bf16(
                        af, bfr[n], acc[mt][n], 0, 0, 0);
            }
            __builtin_amdgcn_s_setprio(0);
        }
        __syncthreads();
    }

    const int rq = (lane >> 4) * 4;
#pragma unroll
    for (int mt = 0; mt < MF; mt++) {
        int row0 = bm * BM + wm * WM + mt * 16 + rq;
#pragma unroll
        for (int n = 0; n < NT; n++) {
            int col = bn * BN + wn * WN + n * 16 + mrow;
            float bvc = (bias && kh == 0) ? bias[col] : 0.f;
#pragma unroll
            for (int r = 0; r < 4; r++) {
                float v = acc[mt][n][r] + bvc;
                if (relu) v = fmaxf(v, 0.f);
                size_t idx = (size_t)(row0 + r) * N + col;
                if (Cf_b) Cf_b[idx] = v;
                if (Cb)   Cb[idx]   = (bf16_t)v;
            }
        }
    }
}

// ---------------------------------------------------------------------------
// 128^2 GEMM (kept for V-projection: M=1024, row-bias, batched).  Swizzled LDS.
// ---------------------------------------------------------------------------
template<int MT>
__global__ __launch_bounds__(256) void gemm_bt(
    const bf16_t* __restrict__ A, const bf16_t* __restrict__ Bt,
    const float* __restrict__ bias,
    float* __restrict__ Cf, bf16_t* __restrict__ Cb,
    int M, int N, int lda, int Kloc, int relu, int nbn, int bias_row,
    long bt_bstride, long c_bstride) {
    constexpr int TM = MT * 32;
    __shared__ __attribute__((aligned(16))) bf16_t As[2][TM * 32];
    __shared__ __attribute__((aligned(16))) bf16_t Bs[2][128 * 32];
    const int tid  = threadIdx.x;
    const int lane = tid & 63;
    const int wave = tid >> 6;
    const int wm = wave & 1, wn = wave >> 1;
    const int kh = blockIdx.z;

    const int span  = 8 * nbn;
    const int group = blockIdx.x / span;
    const int rem   = blockIdx.x % span;
    const int bm    = group * 8 + (rem & 7);
    const int bn    = rem >> 3;

    const bf16_t* Bt_b = Bt + (size_t)blockIdx.y * bt_bstride;
    float*  Cf_b = Cf ? Cf + (size_t)blockIdx.y * c_bstride + (size_t)kh * M * N : nullptr;
    bf16_t* Cb_b = Cb ? Cb + (size_t)blockIdx.y * c_bstride : nullptr;
    const int koff = kh * Kloc;

    const int r4 = tid >> 2;            // 0..63
    const int kcs = ((tid & 3) ^ ((tid >> 3) & 3)) * 8;
    const bf16_t* Ag = A    + (size_t)(bm * TM  + r4) * lda + koff + kcs;
    const bf16_t* Bg = Bt_b + (size_t)(bn * 128 + r4) * lda + koff + kcs;

    f32x4 acc[MT][4] = {};
    const int mrow = lane & 15;
    const int qsw  = (((lane >> 4) ^ ((mrow >> 1) & 3))) * 8;

    auto stage = [&](int kk, int buf) {
#pragma unroll
        for (int i = 0; i < MT / 2; i++)
            gld_lds16(Ag + (size_t)(i * 64) * lda + kk, &As[buf][i * 64 * 32] + tid * 8);
        gld_lds16(Bg + kk,                        &Bs[buf][0] + tid * 8);
        gld_lds16(Bg + (size_t)64 * lda + kk,     &Bs[buf][64 * 32] + tid * 8);
    };

    stage(0, 0);
    __syncthreads();

    const int nt = Kloc >> 5;
    for (int t7 = 0; t7 < nt; ++t7) {
        const int cur = t7 & 1;
        if (t7 + 1 < nt) stage((t7 + 1) << 5, cur ^ 1);

        bf16x8 af[MT], bfr[4];
#pragma unroll
        for (int mt = 0; mt < MT; mt++)
            af[mt] = *(const bf16x8*)(&As[cur][(wm * (MT * 16) + mt * 16 + mrow) * 32 + qsw]);
#pragma unroll
        for (int nt2 = 0; nt2 < 4; nt2++)
            bfr[nt2] = *(const bf16x8*)(&Bs[cur][(wn * 64 + nt2 * 16 + mrow) * 32 + qsw]);
#pragma unroll
        for (int mt = 0; mt < MT; mt++)
#pragma unroll
            for (int nt2 = 0; nt2 < 4; nt2++)
                acc[mt][nt2] = __builtin_amdgcn_mfma_f32_16x16x32_bf16(
                    af[mt], bfr[nt2], acc[mt][nt2], 0, 0, 0);

        __syncthreads();
    }

    const int rq = (lane >> 4) * 4;
#pragma unroll
    for (int mt = 0; mt < MT; mt++) {
        int row0 = bm * TM + wm * (MT * 16) + mt * 16 + rq;
#pragma unroll
        for (int nt2 = 0; nt2 < 4; nt2++) {
            int col = bn * 128 + wn * 64 + nt2 * 16 + mrow;
            float bvc = (bias && kh == 0 && !bias_row) ? bias[col] : 0.f;
#pragma unroll
            for (int r = 0; r < 4; r++) {
                float bb = (bias && kh == 0 && bias_row) ? bias[row0 + r] : bvc;
                float v = acc[mt][nt2][r] + bb;
                if (relu) v = fmaxf(v, 0.f);
                size_t idx = (size_t)(row0 + r) * N + col;
                if (Cf_b) Cf_b[idx] = v;
                if (Cb_b) Cb_b[idx] = (bf16_t)v;
            }
        }
    }
}

// ---------------------------------------------------------------------------
// MFMA flash attention (bf16, no-max softmax, MFMA row-sum).
// QKb [B*S][2048]: q at h*64, k at 1024+h*64.  Vt [B][1024][2048]: row hd.
// v6: QBLK=128, 8 waves, 512 threads; one gld_lds16 per K/V tile; running
// stage pointers; swizzled K/V; Q pre-scaled by C.
// ---------------------------------------------------------------------------
__global__ __launch_bounds__(512) void flash_attn_mfma(
    const bf16_t* __restrict__ QKb,
    const bf16_t* __restrict__ Vtg,
    bf16_t* __restrict__ Outb) {
    __shared__ __attribute__((aligned(16))) bf16_t Ks[2][4096];
    __shared__ __attribute__((aligned(16))) bf16_t Vs[2][4096];
    __shared__ __attribute__((aligned(16))) bf16_t Ps[8192];
    const int t = threadIdx.x;                   // 0..511
    const int lane = t & 63, wave = t >> 6;      // 8 waves
    const int g = lane >> 4, cl = lane & 15;
    const int b = blockIdx.z, h = blockIdx.y, q0 = blockIdx.x * 128;
    const int RS = 2048;
    const bf16_t* Qg = QKb + (size_t)(b * 2048 + q0) * RS + h * 64;
    const bf16_t* Kg = QKb + (size_t)(b * 2048) * RS + 1024 + h * 64;
    const bf16_t* Vg = Vtg + ((size_t)b * 1024 + h * 64) * 2048;

    const int sr   = (t >> 2) & 63;
    const int half = t >> 8;
    const int scs  = half * 32 + (((t & 3) ^ ((t >> 3) & 3)) * 8);

    const float C = 0.125f * 1.4426950408889634f;
    const bf16_t* Qrow = Qg + (size_t)(wave * 16 + cl) * RS;
    bf16x8 qr0 = *(const bf16x8*)(Qrow + g * 8);
    bf16x8 qr1 = *(const bf16x8*)(Qrow + 32 + g * 8);
#pragma unroll
    for (int j = 0; j < 8; j++) {
        qr0[j] = (bf16_t)((float)qr0[j] * C);
        qr1[j] = (bf16_t)((float)qr1[j] * C);
    }

    const bf16_t* Kst = Kg + (size_t)sr * RS + scs;
    const bf16_t* Vst = Vg + (size_t)sr * 2048 + scs;

    gld_lds16(Kst, &Ks[0][0] + t * 8);
    gld_lds16(Vst, &Vs[0][0] + t * 8);
    __syncthreads();

    f32x4 Oacc[4] = {};
    f32x4 Lacc = {};
    bf16x8 ones;
#pragma unroll
    for (int j = 0; j < 8; j++) ones[j] = (bf16_t)1.0f;

    const int rowb = wave * 16 + cl;             // P row 0..127
    const int psw  = (cl & 7) << 4;
    const int gsw  = ((g ^ ((cl >> 1) & 3))) * 8;
    char* PsB = (char*)Ps;

    for (int kt_i = 0; kt_i < 32; ++kt_i) {
        const int cur = kt_i & 1;
        if (kt_i + 1 < 32) {
            Kst += (size_t)64 * RS;
            Vst += 64;
            gld_lds16(Kst, &Ks[cur ^ 1][0] + t * 8);
            gld_lds16(Vst, &Vs[cur ^ 1][0] + t * 8);
        }

        f32x4 Sacc[4] = {};
        __builtin_amdgcn_s_setprio(1);
#pragma unroll
        for (int ks = 0; ks < 2; ++ks) {
            bf16x8 bq = ks ? qr1 : qr0;
#pragma unroll
            for (int mt = 0; mt < 4; ++mt) {
                bf16x8 ak = *(const bf16x8*)(&Ks[cur][ks * 2048 + (mt * 16 + cl) * 32 + gsw]);
                Sacc[mt] = __builtin_amdgcn_mfma_f32_16x16x32_bf16(ak, bq, Sacc[mt], 0, 0, 0);
            }
        }
        __builtin_amdgcn_s_setprio(0);

#pragma unroll
        for (int mt = 0; mt < 4; ++mt) {
            bf16x4 p4;
#pragma unroll
            for (int r = 0; r < 4; r++)
                p4[r] = (bf16_t)__builtin_amdgcn_exp2f(Sacc[mt][r]);
            *(bf16x4*)(PsB + ((rowb * 128 + mt * 32 + g * 8) ^ psw)) = p4;
        }

        __builtin_amdgcn_s_setprio(1);
#pragma unroll
        for (int ks = 0; ks < 2; ++ks) {
            bf16x8 ap = *(const bf16x8*)(PsB + ((rowb * 128 + ks * 64 + g * 16) ^ psw));
            Lacc = __builtin_amdgcn_mfma_f32_16x16x32_bf16(ap, ones, Lacc, 0, 0, 0);
#pragma unroll
            for (int nt = 0; nt < 4; ++nt) {
                bf16x8 bv = *(const bf16x8*)(&Vs[cur][ks * 2048 + (nt * 16 + cl) * 32 + gsw]);
                Oacc[nt] = __builtin_amdgcn_mfma_f32_16x16x32_bf16(ap, bv, Oacc[nt], 0, 0, 0);
            }
        }
        __builtin_amdgcn_s_setprio(0);

        __syncthreads();
    }

#pragma unroll
    for (int r = 0; r < 4; r++) {
        float inv = 1.f / Lacc[r];
        int qrow = q0 + wave * 16 + g * 4 + r;
        size_t base = (size_t)(b * 2048 + qrow) * 1024 + h * 64;
#pragma unroll
        for (int nt = 0; nt < 4; nt++)
            Outb[base + nt * 16 + cl] = (bf16_t)(Oacc[nt][r] * inv);
    }
}

// ---------------------------------------------------------------------------
// out = LN(a + p0 + p1) * g + be ; p1/outb nullable. one block/row, D=1024
// ---------------------------------------------------------------------------
__global__ __launch_bounds__(256) void resid_ln3(const float* __restrict__ a,
                                                 const float* __restrict__ p0,
                                                 const float* __restrict__ p1,
                                                 const float* __restrict__ g,
                                                 const float* __restrict__ be,
                                                 float* __restrict__ outf,
                                                 bf16_t* __restrict__ outb) {
    const int row = blockIdx.x, t = threadIdx.x;
    const size_t base = (size_t)row * 1024;
    f32x4 v = ((const f32x4*)(a + base))[t] + ((const f32x4*)(p0 + base))[t];
    if (p1) v += ((const f32x4*)(p1 + base))[t];
    float sum = v[0] + v[1] + v[2] + v[3];
    float sq  = v[0] * v[0] + v[1] * v[1] + v[2] * v[2] + v[3] * v[3];
#pragma unroll
    for (int o = 1; o < 64; o <<= 1) {
        sum += __shfl_xor(sum, o);
        sq  += __shfl_xor(sq, o);
    }
    __shared__ float red[8];
    int wave = t >> 6, lane = t & 63;
    if (lane == 0) { red[wave] = sum; red[4 + wave] = sq; }
    __syncthreads();
    sum = red[0] + red[1] + red[2] + red[3];
    sq  = red[4] + red[5] + red[6] + red[7];
    float mu  = sum * (1.f / 1024.f);
    float var = sq * (1.f / 1024.f) - mu * mu;
    float rs  = rsqrtf(var + 1e-6f);
    f32x4 g4 = ((const f32x4*)g)[t];
    f32x4 b4 = ((const f32x4*)be)[t];
    f32x4 o = (v - mu) * rs * g4 + b4;
    ((f32x4*)(outf + base))[t] = o;
    if (outb) {
        bf16x4 ob;
        ob[0] = (bf16_t)o[0]; ob[1] = (bf16_t)o[1]; ob[2] = (bf16_t)o[2]; ob[3] = (bf16_t)o[3];
        ((bf16x4*)(outb + base))[t] = ob;
    }
}

// ---------------------------------------------------------------------------
extern "C" void kernel_launch(void* const* d_in, const int* in_sizes, int n_in,
                              void* d_out, int out_size, void* d_ws, size_t ws_size,
                              hipStream_t stream) {
    (void)in_sizes; (void)n_in; (void)out_size; (void)ws_size;
    const float* x   = (const float*)d_in[0];
    const float* wq  = (const float*)d_in[1];
    const float* bq  = (const float*)d_in[2];
    const float* wk  = (const float*)d_in[3];
    const float* bk  = (const float*)d_in[4];
    const float* wv  = (const float*)d_in[5];
    const float* bv  = (const float*)d_in[6];
    const float* wo  = (const float*)d_in[7];
    const float* bo  = (const float*)d_in[8];
    const float* w1  = (const float*)d_in[9];
    const float* b1  = (const float*)d_in[10];
    const float* w2  = (const float*)d_in[11];
    const float* b2  = (const float*)d_in[12];
    const float* g1  = (const float*)d_in[13];
    const float* be1 = (const float*)d_in[14];
    const float* g2  = (const float*)d_in[15];
    const float* be2 = (const float*)d_in[16];
    float* out = (float*)d_out;

    char* ws = (char*)d_ws;
    const size_t MB = 1ull << 20;
    bf16_t* xb    = (bf16_t*)(ws + 0);        //  8MB; reused as ab after V-gemm
    bf16_t* WtQKV = (bf16_t*)(ws + 8 * MB);   //  6MB [q|k|v][1024] rows x 1024
    bf16_t* WtO   = (bf16_t*)(ws + 14 * MB);  //  2MB
    bf16_t* Wt1   = (bf16_t*)(ws + 16 * MB);  //  8MB
    bf16_t* Wt2   = (bf16_t*)(ws + 24 * MB);  //  8MB
    float*  bqkv  = (float*)(ws + 32 * MB);   //  8KB (bq|bk)
    bf16_t* QKb   = (bf16_t*)(ws + 33 * MB);  // 16MB [4096][2048] (dead after attn)
    bf16_t* Vt    = (bf16_t*)(ws + 49 * MB);  //  8MB [2][1024][2048] (dead after attn)
    bf16_t* ffb   = (bf16_t*)(ws + 33 * MB);  // 32MB overlays QKb+Vt
    float*  oa    = (float*)(ws + 65 * MB);   // 32MB: 2 partials (dead after LN1)
    float*  f2    = (float*)(ws + 65 * MB);   // 32MB: 2 partials, overlays oa
    float*  hbuf  = (float*)(ws + 97 * MB);   // 16MB
    bf16_t* hb    = (bf16_t*)(ws + 113 * MB); //  8MB
    bf16_t* ab    = xb;
    const int MN = 4096 * 1024;               // partial-buffer stride

    // 1. prep: transposes (12288 blocks) + cast (4096) + bias pack (1)
    PrepArgs pa;
    pa.w[0] = wq; pa.w[1] = wk; pa.w[2] = wv; pa.w[3] = wo; pa.w[4] = w1; pa.w[5] = w2;
    pa.wt[0] = WtQKV; pa.wt[1] = WtQKV + 1024 * 1024; pa.wt[2] = WtQKV + 2048 * 1024;
    pa.wt[3] = WtO; pa.wt[4] = Wt1; pa.wt[5] = Wt2;
    int Ks[6] = {1024, 1024, 1024, 1024, 1024, 4096};
    int Ns[6] = {1024, 1024, 1024, 1024, 4096, 1024};
    int st[6] = {0, 1024, 2048, 3072, 4096, 8192};
    for (int i = 0; i < 6; i++) { pa.K[i] = Ks[i]; pa.N[i] = Ns[i]; pa.start[i] = st[i]; }
    pa.x = x; pa.xb = xb; pa.castStart = 12288;
    pa.bq = bq; pa.bk = bk; pa.bqkv = bqkv; pa.biasStart = 12288 + 4096;
    prep<<<12288 + 4096 + 1, 256, 0, stream>>>(pa);

    // 2. QK projection -> QKb [4096][2048] bf16  (128x256: 32x8 = 256 blocks)
    gemm_tile<128, 256><<<256, 512, 0, stream>>>(xb, WtQKV, bqkv, nullptr, QKb,
                                        4096, 2048, 1024, 1024, 0, 8);
    // 3. V projection, transposed output: Vt[b][hd][s] = Wv^T * x_b^T  (128^2 path)
    gemm_bt<2><<<dim3(256, 2, 1), 256, 0, stream>>>(WtQKV + 2048 * 1024, xb, bv,
                                        nullptr, Vt, 1024, 2048, 1024, 1024, 0, 16, 1,
                                        (long)2048 * 1024, (long)1024 * 2048);
    // 4. flash attention -> ab (= xb, dead)   (QBLK=128: 16x16x2 blocks, 512 thr)
    flash_attn_mfma<<<dim3(16, 16, 2), 512, 0, stream>>>(QKb, Vt, ab);
    // 5. Wo projection, split-K=2 -> partials oa[0],oa[1] (128x256: 32x4 x z2)
    gemm_tile<128, 256><<<dim3(128, 1, 2), 512, 0, stream>>>(ab, WtO, bo, oa, nullptr,
                                        4096, 1024, 1024, 512, 0, 4);
    // 6. h = LN(x + oa0 + oa1)
    resid_ln3<<<4096, 256, 0, stream>>>(x, oa, oa + MN, g1, be1, hbuf, hb);
    // 7. FF1 + relu -> ffb bf16   (deep-BK32 256x256: 256 blocks)
    gemm_deep<256, 0><<<256, 512, 0, stream>>>(hb, Wt1, b1, nullptr, ffb,
                                        4096, 4096, 1024, 1024, 1, 16);
    // 8. FF2 split-K=4 on the deep engine: zero f2 then kh-pairs atomicAdd
    //    into f2[0],f2[1]  (256x256: 16x4 = 64 blocks x z4 = 256 = 1/CU)
    hipMemsetAsync(f2, 0, (size_t)2 * MN * sizeof(float), stream);
    gemm_deep<256, 1><<<dim3(64, 1, 4), 512, 0, stream>>>(ffb, Wt2, b2, f2, nullptr,
                                        4096, 1024, 4096, 1024, 0, 4);
    // 9. out = LN(h + f2_0 + f2_1)
    resid_ln3<<<4096, 256, 0, stream>>>(hbuf, f2, f2 + MN, g2, be2, out, nullptr);
}

// Round 10
// 372.170 us; speedup vs baseline: 1.1237x; 1.1237x over previous
//
#include <hip/hip_runtime.h>
#include <hip/hip_bf16.h>
#include <cmath>

typedef __bf16 bf16_t;
typedef __bf16 bf16x4 __attribute__((ext_vector_type(4)));
typedef __bf16 bf16x8 __attribute__((ext_vector_type(8)));
typedef float  f32x4  __attribute__((ext_vector_type(4)));

// ---------------------------------------------------------------------------
// async global->LDS, 16B per lane (LDS dest = wave-uniform base + lane*16)
// ---------------------------------------------------------------------------
__device__ __forceinline__ void gld_lds16(const bf16_t* g, bf16_t* l) {
    __builtin_amdgcn_global_load_lds(
        (const __attribute__((address_space(1))) void*)g,
        (__attribute__((address_space(3))) void*)l,
        16, 0, 0);
}

// LDS bank swizzle for 64B-row planes read at row-stride-64B:
//   physical 16B slot = logical slot ^ ((row>>1)&3)   (involution)
// write side: pre-swizzle the GLOBAL source col; read side: XOR same term.

// ---------------------------------------------------------------------------
// prep: ONE launch for x-cast + 6 weight transposes + qk-bias pack
// ---------------------------------------------------------------------------
struct PrepArgs {
    const float* w[6]; bf16_t* wt[6];
    int K[6], N[6], start[6];
    const float* x; bf16_t* xb; int castStart;   // transpose-region end
    const float* bq; const float* bk; float* bqkv; int biasStart;
};

__global__ __launch_bounds__(256) void prep(PrepArgs pa) {
    __shared__ float tile[32][33];
    const int bid = blockIdx.x, t = threadIdx.x;
    if (bid < pa.castStart) {
        int mi = 0;
#pragma unroll
        for (int i = 1; i < 6; i++) if (bid >= pa.start[i]) mi = i;
        const int tt  = bid - pa.start[mi];
        const int nbx = pa.N[mi] >> 5;
        const int n0 = (tt % nbx) * 32, k0 = (tt / nbx) * 32;
        const float* in = pa.w[mi];
        bf16_t* out = pa.wt[mi];
        const int K = pa.K[mi], N = pa.N[mi];
        const int tx = t & 31, ty = t >> 5;
#pragma unroll
        for (int i = 0; i < 4; i++) {
            int kk = ty + i * 8;
            tile[kk][tx] = in[(size_t)(k0 + kk) * N + n0 + tx];
        }
        __syncthreads();
#pragma unroll
        for (int i = 0; i < 4; i++) {
            int nn = ty + i * 8;
            out[(size_t)(n0 + nn) * K + k0 + tx] = (bf16_t)tile[tx][nn];
        }
    } else if (bid < pa.biasStart) {
        int i = (bid - pa.castStart) * 256 + t;
        f32x4 v = ((const f32x4*)pa.x)[i];
        bf16x4 o;
        o[0] = (bf16_t)v[0]; o[1] = (bf16_t)v[1]; o[2] = (bf16_t)v[2]; o[3] = (bf16_t)v[3];
        ((bf16x4*)pa.xb)[i] = o;
    } else {
#pragma unroll
        for (int j = 0; j < 8; j++) {
            int idx = t * 8 + j;
            pa.bqkv[idx] = idx < 1024 ? pa.bq[idx] : pa.bk[idx - 1024];
        }
    }
}

// ---------------------------------------------------------------------------
// Deep-pipelined 256x256 GEMM: BK=32, 4 LDS buffers, depth-3 counted vmcnt
// + swizzled LDS + setprio.  8 waves, 512 thr.  [R4-proven on FF1]
// Split-K via blockIdx.z: bf16 partial written to Cb + kh*M*N (bias only
// kh==0).  z=1 (FF1) degenerates to the original single-output behavior.
// bf16 partial rounding ~4e-4 absolute at this problem's scales — far
// under the 0.05 tolerance, and 4x8MB partials fit the 32MB region that
// two f32 partials used (same write traffic, full 256-block machine fill).
// ---------------------------------------------------------------------------
template<int BN>
__global__ __launch_bounds__(512, 1) void gemm_deep(
    const bf16_t* __restrict__ A, const bf16_t* __restrict__ Bt,
    const float* __restrict__ bias, bf16_t* __restrict__ Cb,
    int M, int N, int lda, int Kloc, int relu, int nbn) {
    constexpr int NT = BN / 64;
    constexpr int WN = BN / 4;
    __shared__ __attribute__((aligned(16))) bf16_t As[4][256 * 32];
    __shared__ __attribute__((aligned(16))) bf16_t Bs[4][BN * 32];
    const int tid  = threadIdx.x;            // 0..511
    const int lane = tid & 63;
    const int wave = tid >> 6;               // 0..7
    const int wm = wave >> 2, wn = wave & 3; // 2M x 4N
    const int kh = blockIdx.z;

    const int span  = 8 * nbn;
    const int group = blockIdx.x / span;
    const int rem   = blockIdx.x % span;
    const int bm    = group * 8 + (rem & 7);
    const int bn    = rem >> 3;

    bf16_t* Cb_b = Cb + (size_t)kh * M * N;
    const int koff = kh * Kloc;

    const int srow   = tid >> 2;
    const int slot_s = ((tid & 3) ^ ((tid >> 3) & 3)) * 8;
    const bf16_t* Ag = A  + (size_t)(bm * 256 + srow) * lda + koff + slot_s;
    const bf16_t* Bg = Bt + (size_t)(bn * BN  + srow) * lda + koff + slot_s;

    auto stage = [&](int kk, int buf) {
        gld_lds16(Ag + kk,                       &As[buf][0]        + tid * 8);
        gld_lds16(Ag + (size_t)128 * lda + kk,   &As[buf][128 * 32] + tid * 8);
        gld_lds16(Bg + kk,                       &Bs[buf][0]        + tid * 8);
        if constexpr (BN == 256)
            gld_lds16(Bg + (size_t)128 * lda + kk, &Bs[buf][128 * 32] + tid * 8);
    };

    f32x4 acc[8][NT] = {};
    const int mrow = lane & 15;
    const int qsw  = (((lane >> 4) ^ ((mrow >> 1) & 3))) * 8;

    auto compute = [&](int cur) {
        bf16x8 bfr[NT], af[8];
#pragma unroll
        for (int n = 0; n < NT; n++)
            bfr[n] = *(const bf16x8*)(&Bs[cur][(wn * WN + n * 16 + mrow) * 32 + qsw]);
#pragma unroll
        for (int mt = 0; mt < 8; mt++)
            af[mt] = *(const bf16x8*)(&As[cur][(wm * 128 + mt * 16 + mrow) * 32 + qsw]);
        __builtin_amdgcn_s_setprio(1);
#pragma unroll
        for (int mt = 0; mt < 8; mt++)
#pragma unroll
            for (int n = 0; n < NT; n++)
                acc[mt][n] = __builtin_amdgcn_mfma_f32_16x16x32_bf16(
                    af[mt], bfr[n], acc[mt][n], 0, 0, 0);
        __builtin_amdgcn_s_setprio(0);
    };

    stage(0, 0); stage(32, 1); stage(64, 2);
    const int nst = Kloc >> 5;               // >= 8 at every call site
    for (int t = 0; t + 3 < nst; ++t) {
        stage((t + 3) * 32, (t + 3) & 3);
        if constexpr (BN == 256) asm volatile("s_waitcnt vmcnt(12)" ::: "memory");
        else                     asm volatile("s_waitcnt vmcnt(9)"  ::: "memory");
        __builtin_amdgcn_s_barrier();
        compute(t & 3);
        asm volatile("s_waitcnt lgkmcnt(0)" ::: "memory");
        __builtin_amdgcn_s_barrier();
    }
    if constexpr (BN == 256) asm volatile("s_waitcnt vmcnt(8)" ::: "memory");
    else                     asm volatile("s_waitcnt vmcnt(6)" ::: "memory");
    __builtin_amdgcn_s_barrier();
    compute((nst - 3) & 3);
    asm volatile("s_waitcnt lgkmcnt(0)" ::: "memory");
    __builtin_amdgcn_s_barrier();
    if constexpr (BN == 256) asm volatile("s_waitcnt vmcnt(4)" ::: "memory");
    else                     asm volatile("s_waitcnt vmcnt(3)" ::: "memory");
    __builtin_amdgcn_s_barrier();
    compute((nst - 2) & 3);
    asm volatile("s_waitcnt lgkmcnt(0)" ::: "memory");
    __builtin_amdgcn_s_barrier();
    asm volatile("s_waitcnt vmcnt(0)" ::: "memory");
    __builtin_amdgcn_s_barrier();
    compute((nst - 1) & 3);

    const int rq = (lane >> 4) * 4;
#pragma unroll
    for (int mt = 0; mt < 8; mt++) {
        int row0 = bm * 256 + wm * 128 + mt * 16 + rq;
#pragma unroll
        for (int n = 0; n < NT; n++) {
            int col = bn * BN + wn * WN + n * 16 + mrow;
            float bvc = (bias && kh == 0) ? bias[col] : 0.f;
#pragma unroll
            for (int r = 0; r < 4; r++) {
                float v = acc[mt][n][r] + bvc;
                if (relu) v = fmaxf(v, 0.f);
                Cb_b[(size_t)(row0 + r) * N + col] = (bf16_t)v;
            }
        }
    }
}

// ---------------------------------------------------------------------------
// 128x256 big-tile GEMM, BK=64, 2-phase dbuf (QK).  Swizzled LDS.
// ---------------------------------------------------------------------------
template<int BM, int BN>
__global__ __launch_bounds__(512, 2) void gemm_tile(
    const bf16_t* __restrict__ A, const bf16_t* __restrict__ Bt,
    const float* __restrict__ bias,
    float* __restrict__ Cf, bf16_t* __restrict__ Cb,
    int M, int N, int lda, int Kloc, int relu, int nbn) {
    constexpr int MF = BM / 32;
    constexpr int NT = BN / 64;
    constexpr int WM = BM / 2;
    constexpr int WN = BN / 4;
    __shared__ __attribute__((aligned(16))) bf16_t As[2][2][BM * 32];
    __shared__ __attribute__((aligned(16))) bf16_t Bs[2][2][BN * 32];
    const int tid  = threadIdx.x;
    const int lane = tid & 63;
    const int wave = tid >> 6;
    const int wm = wave >> 2, wn = wave & 3;
    const int kh = blockIdx.z;

    const int span  = 8 * nbn;
    const int group = blockIdx.x / span;
    const int rem   = blockIdx.x % span;
    const int bm    = group * 8 + (rem & 7);
    const int bn    = rem >> 3;

    float*  Cf_b = Cf ? Cf + (size_t)kh * M * N : nullptr;
    const int koff = kh * Kloc;

    const int r4 = tid >> 2;
    const int kcs = ((tid & 3) ^ ((tid >> 3) & 3)) * 8;
    const bf16_t* Ag = A  + (size_t)(bm * BM + r4) * lda + koff + kcs;
    const bf16_t* Bg = Bt + (size_t)(bn * BN + r4) * lda + koff + kcs;

    f32x4 acc[MF][NT] = {};
    const int mrow = lane & 15;
    const int qsw  = (((lane >> 4) ^ ((mrow >> 1) & 3))) * 8;

    auto stage = [&](int kk, int buf) {
#pragma unroll
        for (int hh = 0; hh < 2; hh++) {
#pragma unroll
            for (int i = 0; i < BM / 128; i++)
                gld_lds16(Ag + (size_t)(i * 128) * lda + kk + hh * 32,
                          &As[buf][hh][i * 128 * 32] + tid * 8);
#pragma unroll
            for (int i = 0; i < BN / 128; i++)
                gld_lds16(Bg + (size_t)(i * 128) * lda + kk + hh * 32,
                          &Bs[buf][hh][i * 128 * 32] + tid * 8);
        }
    };

    stage(0, 0);
    __syncthreads();

    const int nsteps = Kloc >> 6;
    for (int st = 0; st < nsteps; ++st) {
        const int cur = st & 1;
        if (st + 1 < nsteps) stage((st + 1) << 6, cur ^ 1);

#pragma unroll
        for (int hh = 0; hh < 2; hh++) {
            bf16x8 bfr[NT];
#pragma unroll
            for (int n = 0; n < NT; n++)
                bfr[n] = *(const bf16x8*)(&Bs[cur][hh][(wn * WN + n * 16 + mrow) * 32 + qsw]);
            __builtin_amdgcn_s_setprio(1);
#pragma unroll
            for (int mt = 0; mt < MF; mt++) {
                bf16x8 af = *(const bf16x8*)(&As[cur][hh][(wm * WM + mt * 16 + mrow) * 32 + qsw]);
#pragma unroll
                for (int n = 0; n < NT; n++)
                    acc[mt][n] = __builtin_amdgcn_mfma_f32_16x16x32_bf16(
                        af, bfr[n], acc[mt][n], 0, 0, 0);
            }
            __builtin_amdgcn_s_setprio(0);
        }
        __syncthreads();
    }

    const int rq = (lane >> 4) * 4;
#pragma unroll
    for (int mt = 0; mt < MF; mt++) {
        int row0 = bm * BM + wm * WM + mt * 16 + rq;
#pragma unroll
        for (int n = 0; n < NT; n++) {
            int col = bn * BN + wn * WN + n * 16 + mrow;
            float bvc = (bias && kh == 0) ? bias[col] : 0.f;
#pragma unroll
            for (int r = 0; r < 4; r++) {
                float v = acc[mt][n][r] + bvc;
                if (relu) v = fmaxf(v, 0.f);
                size_t idx = (size_t)(row0 + r) * N + col;
                if (Cf_b) Cf_b[idx] = v;
                if (Cb)   Cb[idx]   = (bf16_t)v;
            }
        }
    }
}

// ---------------------------------------------------------------------------
// 128^2 GEMM (kept for V-projection: M=1024, row-bias, batched).  Swizzled LDS.
// ---------------------------------------------------------------------------
template<int MT>
__global__ __launch_bounds__(256) void gemm_bt(
    const bf16_t* __restrict__ A, const bf16_t* __restrict__ Bt,
    const float* __restrict__ bias,
    float* __restrict__ Cf, bf16_t* __restrict__ Cb,
    int M, int N, int lda, int Kloc, int relu, int nbn, int bias_row,
    long bt_bstride, long c_bstride) {
    constexpr int TM = MT * 32;
    __shared__ __attribute__((aligned(16))) bf16_t As[2][TM * 32];
    __shared__ __attribute__((aligned(16))) bf16_t Bs[2][128 * 32];
    const int tid  = threadIdx.x;
    const int lane = tid & 63;
    const int wave = tid >> 6;
    const int wm = wave & 1, wn = wave >> 1;
    const int kh = blockIdx.z;

    const int span  = 8 * nbn;
    const int group = blockIdx.x / span;
    const int rem   = blockIdx.x % span;
    const int bm    = group * 8 + (rem & 7);
    const int bn    = rem >> 3;

    const bf16_t* Bt_b = Bt + (size_t)blockIdx.y * bt_bstride;
    float*  Cf_b = Cf ? Cf + (size_t)blockIdx.y * c_bstride + (size_t)kh * M * N : nullptr;
    bf16_t* Cb_b = Cb ? Cb + (size_t)blockIdx.y * c_bstride : nullptr;
    const int koff = kh * Kloc;

    const int r4 = tid >> 2;            // 0..63
    const int kcs = ((tid & 3) ^ ((tid >> 3) & 3)) * 8;
    const bf16_t* Ag = A    + (size_t)(bm * TM  + r4) * lda + koff + kcs;
    const bf16_t* Bg = Bt_b + (size_t)(bn * 128 + r4) * lda + koff + kcs;

    f32x4 acc[MT][4] = {};
    const int mrow = lane & 15;
    const int qsw  = (((lane >> 4) ^ ((mrow >> 1) & 3))) * 8;

    auto stage = [&](int kk, int buf) {
#pragma unroll
        for (int i = 0; i < MT / 2; i++)
            gld_lds16(Ag + (size_t)(i * 64) * lda + kk, &As[buf][i * 64 * 32] + tid * 8);
        gld_lds16(Bg + kk,                        &Bs[buf][0] + tid * 8);
        gld_lds16(Bg + (size_t)64 * lda + kk,     &Bs[buf][64 * 32] + tid * 8);
    };

    stage(0, 0);
    __syncthreads();

    const int nt = Kloc >> 5;
    for (int t7 = 0; t7 < nt; ++t7) {
        const int cur = t7 & 1;
        if (t7 + 1 < nt) stage((t7 + 1) << 5, cur ^ 1);

        bf16x8 af[MT], bfr[4];
#pragma unroll
        for (int mt = 0; mt < MT; mt++)
            af[mt] = *(const bf16x8*)(&As[cur][(wm * (MT * 16) + mt * 16 + mrow) * 32 + qsw]);
#pragma unroll
        for (int nt2 = 0; nt2 < 4; nt2++)
            bfr[nt2] = *(const bf16x8*)(&Bs[cur][(wn * 64 + nt2 * 16 + mrow) * 32 + qsw]);
#pragma unroll
        for (int mt = 0; mt < MT; mt++)
#pragma unroll
            for (int nt2 = 0; nt2 < 4; nt2++)
                acc[mt][nt2] = __builtin_amdgcn_mfma_f32_16x16x32_bf16(
                    af[mt], bfr[nt2], acc[mt][nt2], 0, 0, 0);

        __syncthreads();
    }

    const int rq = (lane >> 4) * 4;
#pragma unroll
    for (int mt = 0; mt < MT; mt++) {
        int row0 = bm * TM + wm * (MT * 16) + mt * 16 + rq;
#pragma unroll
        for (int nt2 = 0; nt2 < 4; nt2++) {
            int col = bn * 128 + wn * 64 + nt2 * 16 + mrow;
            float bvc = (bias && kh == 0 && !bias_row) ? bias[col] : 0.f;
#pragma unroll
            for (int r = 0; r < 4; r++) {
                float bb = (bias && kh == 0 && bias_row) ? bias[row0 + r] : bvc;
                float v = acc[mt][nt2][r] + bb;
                if (relu) v = fmaxf(v, 0.f);
                size_t idx = (size_t)(row0 + r) * N + col;
                if (Cf_b) Cf_b[idx] = v;
                if (Cb_b) Cb_b[idx] = (bf16_t)v;
            }
        }
    }
}

// ---------------------------------------------------------------------------
// MFMA flash attention (bf16, no-max softmax, MFMA row-sum).
// QKb [B*S][2048]: q at h*64, k at 1024+h*64.  Vt [B][1024][2048]: row hd.
// v6: QBLK=128, 8 waves, 512 threads; one gld_lds16 per K/V tile; running
// stage pointers; swizzled K/V; Q pre-scaled by C.
// ---------------------------------------------------------------------------
__global__ __launch_bounds__(512) void flash_attn_mfma(
    const bf16_t* __restrict__ QKb,
    const bf16_t* __restrict__ Vtg,
    bf16_t* __restrict__ Outb) {
    __shared__ __attribute__((aligned(16))) bf16_t Ks[2][4096];
    __shared__ __attribute__((aligned(16))) bf16_t Vs[2][4096];
    __shared__ __attribute__((aligned(16))) bf16_t Ps[8192];
    const int t = threadIdx.x;                   // 0..511
    const int lane = t & 63, wave = t >> 6;      // 8 waves
    const int g = lane >> 4, cl = lane & 15;
    const int b = blockIdx.z, h = blockIdx.y, q0 = blockIdx.x * 128;
    const int RS = 2048;
    const bf16_t* Qg = QKb + (size_t)(b * 2048 + q0) * RS + h * 64;
    const bf16_t* Kg = QKb + (size_t)(b * 2048) * RS + 1024 + h * 64;
    const bf16_t* Vg = Vtg + ((size_t)b * 1024 + h * 64) * 2048;

    const int sr   = (t >> 2) & 63;
    const int half = t >> 8;
    const int scs  = half * 32 + (((t & 3) ^ ((t >> 3) & 3)) * 8);

    const float C = 0.125f * 1.4426950408889634f;
    const bf16_t* Qrow = Qg + (size_t)(wave * 16 + cl) * RS;
    bf16x8 qr0 = *(const bf16x8*)(Qrow + g * 8);
    bf16x8 qr1 = *(const bf16x8*)(Qrow + 32 + g * 8);
#pragma unroll
    for (int j = 0; j < 8; j++) {
        qr0[j] = (bf16_t)((float)qr0[j] * C);
        qr1[j] = (bf16_t)((float)qr1[j] * C);
    }

    const bf16_t* Kst = Kg + (size_t)sr * RS + scs;
    const bf16_t* Vst = Vg + (size_t)sr * 2048 + scs;

    gld_lds16(Kst, &Ks[0][0] + t * 8);
    gld_lds16(Vst, &Vs[0][0] + t * 8);
    __syncthreads();

    f32x4 Oacc[4] = {};
    f32x4 Lacc = {};
    bf16x8 ones;
#pragma unroll
    for (int j = 0; j < 8; j++) ones[j] = (bf16_t)1.0f;

    const int rowb = wave * 16 + cl;             // P row 0..127
    const int psw  = (cl & 7) << 4;
    const int gsw  = ((g ^ ((cl >> 1) & 3))) * 8;
    char* PsB = (char*)Ps;

    for (int kt_i = 0; kt_i < 32; ++kt_i) {
        const int cur = kt_i & 1;
        if (kt_i + 1 < 32) {
            Kst += (size_t)64 * RS;
            Vst += 64;
            gld_lds16(Kst, &Ks[cur ^ 1][0] + t * 8);
            gld_lds16(Vst, &Vs[cur ^ 1][0] + t * 8);
        }

        f32x4 Sacc[4] = {};
        __builtin_amdgcn_s_setprio(1);
#pragma unroll
        for (int ks = 0; ks < 2; ++ks) {
            bf16x8 bq = ks ? qr1 : qr0;
#pragma unroll
            for (int mt = 0; mt < 4; ++mt) {
                bf16x8 ak = *(const bf16x8*)(&Ks[cur][ks * 2048 + (mt * 16 + cl) * 32 + gsw]);
                Sacc[mt] = __builtin_amdgcn_mfma_f32_16x16x32_bf16(ak, bq, Sacc[mt], 0, 0, 0);
            }
        }
        __builtin_amdgcn_s_setprio(0);

#pragma unroll
        for (int mt = 0; mt < 4; ++mt) {
            bf16x4 p4;
#pragma unroll
            for (int r = 0; r < 4; r++)
                p4[r] = (bf16_t)__builtin_amdgcn_exp2f(Sacc[mt][r]);
            *(bf16x4*)(PsB + ((rowb * 128 + mt * 32 + g * 8) ^ psw)) = p4;
        }

        __builtin_amdgcn_s_setprio(1);
#pragma unroll
        for (int ks = 0; ks < 2; ++ks) {
            bf16x8 ap = *(const bf16x8*)(PsB + ((rowb * 128 + ks * 64 + g * 16) ^ psw));
            Lacc = __builtin_amdgcn_mfma_f32_16x16x32_bf16(ap, ones, Lacc, 0, 0, 0);
#pragma unroll
            for (int nt = 0; nt < 4; ++nt) {
                bf16x8 bv = *(const bf16x8*)(&Vs[cur][ks * 2048 + (nt * 16 + cl) * 32 + gsw]);
                Oacc[nt] = __builtin_amdgcn_mfma_f32_16x16x32_bf16(ap, bv, Oacc[nt], 0, 0, 0);
            }
        }
        __builtin_amdgcn_s_setprio(0);

        __syncthreads();
    }

#pragma unroll
    for (int r = 0; r < 4; r++) {
        float inv = 1.f / Lacc[r];
        int qrow = q0 + wave * 16 + g * 4 + r;
        size_t base = (size_t)(b * 2048 + qrow) * 1024 + h * 64;
#pragma unroll
        for (int nt = 0; nt < 4; nt++)
            Outb[base + nt * 16 + cl] = (bf16_t)(Oacc[nt][r] * inv);
    }
}

// ---------------------------------------------------------------------------
// out = LN(a + p0 + p1 + p2 + p3) * g + be ; p* = bf16 split-K partials at
// stride pstr.  outb nullable.  one block/row, D=1024.
// ---------------------------------------------------------------------------
__global__ __launch_bounds__(256) void resid_ln4(const float* __restrict__ a,
                                                 const bf16_t* __restrict__ p,
                                                 long pstr,
                                                 const float* __restrict__ g,
                                                 const float* __restrict__ be,
                                                 float* __restrict__ outf,
                                                 bf16_t* __restrict__ outb) {
    const int row = blockIdx.x, t = threadIdx.x;
    const size_t base = (size_t)row * 1024;
    f32x4 v = ((const f32x4*)(a + base))[t];
#pragma unroll
    for (int j = 0; j < 4; j++) {
        bf16x4 pv = ((const bf16x4*)(p + (size_t)j * pstr + base))[t];
        v[0] += (float)pv[0]; v[1] += (float)pv[1];
        v[2] += (float)pv[2]; v[3] += (float)pv[3];
    }
    float sum = v[0] + v[1] + v[2] + v[3];
    float sq  = v[0] * v[0] + v[1] * v[1] + v[2] * v[2] + v[3] * v[3];
#pragma unroll
    for (int o = 1; o < 64; o <<= 1) {
        sum += __shfl_xor(sum, o);
        sq  += __shfl_xor(sq, o);
    }
    __shared__ float red[8];
    int wave = t >> 6, lane = t & 63;
    if (lane == 0) { red[wave] = sum; red[4 + wave] = sq; }
    __syncthreads();
    sum = red[0] + red[1] + red[2] + red[3];
    sq  = red[4] + red[5] + red[6] + red[7];
    float mu  = sum * (1.f / 1024.f);
    float var = sq * (1.f / 1024.f) - mu * mu;
    float rs  = rsqrtf(var + 1e-6f);
    f32x4 g4 = ((const f32x4*)g)[t];
    f32x4 b4 = ((const f32x4*)be)[t];
    f32x4 o = (v - mu) * rs * g4 + b4;
    ((f32x4*)(outf + base))[t] = o;
    if (outb) {
        bf16x4 ob;
        ob[0] = (bf16_t)o[0]; ob[1] = (bf16_t)o[1]; ob[2] = (bf16_t)o[2]; ob[3] = (bf16_t)o[3];
        ((bf16x4*)(outb + base))[t] = ob;
    }
}

// ---------------------------------------------------------------------------
extern "C" void kernel_launch(void* const* d_in, const int* in_sizes, int n_in,
                              void* d_out, int out_size, void* d_ws, size_t ws_size,
                              hipStream_t stream) {
    (void)in_sizes; (void)n_in; (void)out_size; (void)ws_size;
    const float* x   = (const float*)d_in[0];
    const float* wq  = (const float*)d_in[1];
    const float* bq  = (const float*)d_in[2];
    const float* wk  = (const float*)d_in[3];
    const float* bk  = (const float*)d_in[4];
    const float* wv  = (const float*)d_in[5];
    const float* bv  = (const float*)d_in[6];
    const float* wo  = (const float*)d_in[7];
    const float* bo  = (const float*)d_in[8];
    const float* w1  = (const float*)d_in[9];
    const float* b1  = (const float*)d_in[10];
    const float* w2  = (const float*)d_in[11];
    const float* b2  = (const float*)d_in[12];
    const float* g1  = (const float*)d_in[13];
    const float* be1 = (const float*)d_in[14];
    const float* g2  = (const float*)d_in[15];
    const float* be2 = (const float*)d_in[16];
    float* out = (float*)d_out;

    char* ws = (char*)d_ws;
    const size_t MB = 1ull << 20;
    bf16_t* xb    = (bf16_t*)(ws + 0);        //  8MB; reused as ab after V-gemm
    bf16_t* WtQKV = (bf16_t*)(ws + 8 * MB);   //  6MB [q|k|v][1024] rows x 1024
    bf16_t* WtO   = (bf16_t*)(ws + 14 * MB);  //  2MB
    bf16_t* Wt1   = (bf16_t*)(ws + 16 * MB);  //  8MB
    bf16_t* Wt2   = (bf16_t*)(ws + 24 * MB);  //  8MB
    float*  bqkv  = (float*)(ws + 32 * MB);   //  8KB (bq|bk)
    bf16_t* QKb   = (bf16_t*)(ws + 33 * MB);  // 16MB [4096][2048] (dead after attn)
    bf16_t* Vt    = (bf16_t*)(ws + 49 * MB);  //  8MB [2][1024][2048] (dead after attn)
    bf16_t* ffb   = (bf16_t*)(ws + 33 * MB);  // 32MB overlays QKb+Vt
    bf16_t* oab   = (bf16_t*)(ws + 65 * MB);  // 32MB: 4 bf16 partials (dead after LN1)
    bf16_t* f2b   = (bf16_t*)(ws + 65 * MB);  // 32MB: 4 bf16 partials, overlays oab
    float*  hbuf  = (float*)(ws + 97 * MB);   // 16MB
    bf16_t* hb    = (bf16_t*)(ws + 113 * MB); //  8MB
    bf16_t* ab    = xb;
    const long MN = 4096 * 1024;              // partial-buffer stride (elements)

    // 1. prep: transposes (12288 blocks) + cast (4096) + bias pack (1)
    PrepArgs pa;
    pa.w[0] = wq; pa.w[1] = wk; pa.w[2] = wv; pa.w[3] = wo; pa.w[4] = w1; pa.w[5] = w2;
    pa.wt[0] = WtQKV; pa.wt[1] = WtQKV + 1024 * 1024; pa.wt[2] = WtQKV + 2048 * 1024;
    pa.wt[3] = WtO; pa.wt[4] = Wt1; pa.wt[5] = Wt2;
    int Ks[6] = {1024, 1024, 1024, 1024, 1024, 4096};
    int Ns[6] = {1024, 1024, 1024, 1024, 4096, 1024};
    int st[6] = {0, 1024, 2048, 3072, 4096, 8192};
    for (int i = 0; i < 6; i++) { pa.K[i] = Ks[i]; pa.N[i] = Ns[i]; pa.start[i] = st[i]; }
    pa.x = x; pa.xb = xb; pa.castStart = 12288;
    pa.bq = bq; pa.bk = bk; pa.bqkv = bqkv; pa.biasStart = 12288 + 4096;
    prep<<<12288 + 4096 + 1, 256, 0, stream>>>(pa);

    // 2. QK projection -> QKb [4096][2048] bf16  (128x256: 32x8 = 256 blocks)
    gemm_tile<128, 256><<<256, 512, 0, stream>>>(xb, WtQKV, bqkv, nullptr, QKb,
                                        4096, 2048, 1024, 1024, 0, 8);
    // 3. V projection, transposed output: Vt[b][hd][s] = Wv^T * x_b^T  (128^2 path)
    gemm_bt<2><<<dim3(256, 2, 1), 256, 0, stream>>>(WtQKV + 2048 * 1024, xb, bv,
                                        nullptr, Vt, 1024, 2048, 1024, 1024, 0, 16, 1,
                                        (long)2048 * 1024, (long)1024 * 2048);
    // 4. flash attention -> ab (= xb, dead)   (QBLK=128: 16x16x2 blocks, 512 thr)
    flash_attn_mfma<<<dim3(16, 16, 2), 512, 0, stream>>>(QKb, Vt, ab);
    // 5. Wo projection, split-K=4 -> 4 bf16 partials (deep engine, 64x4 = 256 blk)
    gemm_deep<256><<<dim3(64, 1, 4), 512, 0, stream>>>(ab, WtO, bo, oab,
                                        4096, 1024, 1024, 256, 0, 4);
    // 6. h = LN(x + Σ oab[0..3])
    resid_ln4<<<4096, 256, 0, stream>>>(x, oab, MN, g1, be1, hbuf, hb);
    // 7. FF1 + relu -> ffb bf16   (deep-BK32 256x256: 256 blocks)
    gemm_deep<256><<<256, 512, 0, stream>>>(hb, Wt1, b1, ffb,
                                        4096, 4096, 1024, 1024, 1, 16);
    // 8. FF2 split-K=4 -> 4 bf16 partials (deep engine, 64x4 = 256 blocks)
    gemm_deep<256><<<dim3(64, 1, 4), 512, 0, stream>>>(ffb, Wt2, b2, f2b,
                                        4096, 1024, 4096, 1024, 0, 4);
    // 9. out = LN(h + Σ f2b[0..3])
    resid_ln4<<<4096, 256, 0, stream>>>(hbuf, f2b, MN, g2, be2, out, nullptr);
}

// Round 11
// 371.442 us; speedup vs baseline: 1.1259x; 1.0020x over previous
//
#include <hip/hip_runtime.h>
#include <hip/hip_bf16.h>
#include <cmath>

typedef __bf16 bf16_t;
typedef __bf16 bf16x4 __attribute__((ext_vector_type(4)));
typedef __bf16 bf16x8 __attribute__((ext_vector_type(8)));
typedef float  f32x4  __attribute__((ext_vector_type(4)));

// ---------------------------------------------------------------------------
// async global->LDS, 16B per lane (LDS dest = wave-uniform base + lane*16)
// ---------------------------------------------------------------------------
__device__ __forceinline__ void gld_lds16(const bf16_t* g, bf16_t* l) {
    __builtin_amdgcn_global_load_lds(
        (const __attribute__((address_space(1))) void*)g,
        (__attribute__((address_space(3))) void*)l,
        16, 0, 0);
}

// T1 XCD-aware chunked swizzle: HW round-robins linear block id across the 8
// XCD L2s; remap so XCD j owns a CONTIGUOUS logical chunk -> panel/KV re-reads
// become private-L2 hits instead of LLC traffic.  Bijective when nwg%8==0
// (all grids here are).  logical = (flat%8)*(nwg/8) + flat/8.

// ---------------------------------------------------------------------------
// prep: ONE launch for x-cast + 6 weight transposes + qk-bias pack
// ---------------------------------------------------------------------------
struct PrepArgs {
    const float* w[6]; bf16_t* wt[6];
    int K[6], N[6], start[6];
    const float* x; bf16_t* xb; int castStart;   // transpose-region end
    const float* bq; const float* bk; float* bqkv; int biasStart;
};

__global__ __launch_bounds__(256) void prep(PrepArgs pa) {
    __shared__ float tile[32][33];
    const int bid = blockIdx.x, t = threadIdx.x;
    if (bid < pa.castStart) {
        int mi = 0;
#pragma unroll
        for (int i = 1; i < 6; i++) if (bid >= pa.start[i]) mi = i;
        const int tt  = bid - pa.start[mi];
        const int nbx = pa.N[mi] >> 5;
        const int n0 = (tt % nbx) * 32, k0 = (tt / nbx) * 32;
        const float* in = pa.w[mi];
        bf16_t* out = pa.wt[mi];
        const int K = pa.K[mi], N = pa.N[mi];
        const int tx = t & 31, ty = t >> 5;
#pragma unroll
        for (int i = 0; i < 4; i++) {
            int kk = ty + i * 8;
            tile[kk][tx] = in[(size_t)(k0 + kk) * N + n0 + tx];
        }
        __syncthreads();
#pragma unroll
        for (int i = 0; i < 4; i++) {
            int nn = ty + i * 8;
            out[(size_t)(n0 + nn) * K + k0 + tx] = (bf16_t)tile[tx][nn];
        }
    } else if (bid < pa.biasStart) {
        int i = (bid - pa.castStart) * 256 + t;
        f32x4 v = ((const f32x4*)pa.x)[i];
        bf16x4 o;
        o[0] = (bf16_t)v[0]; o[1] = (bf16_t)v[1]; o[2] = (bf16_t)v[2]; o[3] = (bf16_t)v[3];
        ((bf16x4*)pa.xb)[i] = o;
    } else {
#pragma unroll
        for (int j = 0; j < 8; j++) {
            int idx = t * 8 + j;
            pa.bqkv[idx] = idx < 1024 ? pa.bq[idx] : pa.bk[idx - 1024];
        }
    }
}

// ---------------------------------------------------------------------------
// Deep-pipelined 256x256 GEMM (FF1, Wo): BK=32, 4 LDS buffers, depth-3
// counted vmcnt + swizzled LDS + setprio.  8 waves, 512 thr.  [R4-proven]
// Split-K via z: bf16 partial at Cb + kh*M*N (bias only kh==0).
// v11: + T1 XCD chunked swizzle over the flattened (x,z) grid.
// ---------------------------------------------------------------------------
template<int BN>
__global__ __launch_bounds__(512, 1) void gemm_deep(
    const bf16_t* __restrict__ A, const bf16_t* __restrict__ Bt,
    const float* __restrict__ bias, bf16_t* __restrict__ Cb,
    int M, int N, int lda, int Kloc, int relu, int nbn) {
    constexpr int NT = BN / 64;
    constexpr int WN = BN / 4;
    __shared__ __attribute__((aligned(16))) bf16_t As[4][256 * 32];
    __shared__ __attribute__((aligned(16))) bf16_t Bs[4][BN * 32];
    const int tid  = threadIdx.x;            // 0..511
    const int lane = tid & 63;
    const int wave = tid >> 6;               // 0..7
    const int wm = wave >> 2, wn = wave & 3; // 2M x 4N

    // T1: chunked XCD swizzle over flattened grid (nwg % 8 == 0 at all sites)
    const int nwgx = gridDim.x;
    const int flat = blockIdx.x + nwgx * blockIdx.z;
    const int nwg  = nwgx * gridDim.z;
    const int logical = (flat & 7) * (nwg >> 3) + (flat >> 3);
    const int lx = logical % nwgx;
    const int kh = logical / nwgx;

    const int span  = 8 * nbn;
    const int group = lx / span;
    const int rem   = lx % span;
    const int bm    = group * 8 + (rem & 7);
    const int bn    = rem >> 3;

    bf16_t* Cb_b = Cb + (size_t)kh * M * N;
    const int koff = kh * Kloc;

    const int srow   = tid >> 2;
    const int slot_s = ((tid & 3) ^ ((tid >> 3) & 3)) * 8;
    const bf16_t* Ag = A  + (size_t)(bm * 256 + srow) * lda + koff + slot_s;
    const bf16_t* Bg = Bt + (size_t)(bn * BN  + srow) * lda + koff + slot_s;

    auto stage = [&](int kk, int buf) {
        gld_lds16(Ag + kk,                       &As[buf][0]        + tid * 8);
        gld_lds16(Ag + (size_t)128 * lda + kk,   &As[buf][128 * 32] + tid * 8);
        gld_lds16(Bg + kk,                       &Bs[buf][0]        + tid * 8);
        if constexpr (BN == 256)
            gld_lds16(Bg + (size_t)128 * lda + kk, &Bs[buf][128 * 32] + tid * 8);
    };

    f32x4 acc[8][NT] = {};
    const int mrow = lane & 15;
    const int qsw  = (((lane >> 4) ^ ((mrow >> 1) & 3))) * 8;

    auto compute = [&](int cur) {
        bf16x8 bfr[NT], af[8];
#pragma unroll
        for (int n = 0; n < NT; n++)
            bfr[n] = *(const bf16x8*)(&Bs[cur][(wn * WN + n * 16 + mrow) * 32 + qsw]);
#pragma unroll
        for (int mt = 0; mt < 8; mt++)
            af[mt] = *(const bf16x8*)(&As[cur][(wm * 128 + mt * 16 + mrow) * 32 + qsw]);
        __builtin_amdgcn_s_setprio(1);
#pragma unroll
        for (int mt = 0; mt < 8; mt++)
#pragma unroll
            for (int n = 0; n < NT; n++)
                acc[mt][n] = __builtin_amdgcn_mfma_f32_16x16x32_bf16(
                    af[mt], bfr[n], acc[mt][n], 0, 0, 0);
        __builtin_amdgcn_s_setprio(0);
    };

    stage(0, 0); stage(32, 1); stage(64, 2);
    const int nst = Kloc >> 5;               // >= 8 at every call site
    for (int t = 0; t + 3 < nst; ++t) {
        stage((t + 3) * 32, (t + 3) & 3);
        if constexpr (BN == 256) asm volatile("s_waitcnt vmcnt(12)" ::: "memory");
        else                     asm volatile("s_waitcnt vmcnt(9)"  ::: "memory");
        __builtin_amdgcn_s_barrier();
        compute(t & 3);
        asm volatile("s_waitcnt lgkmcnt(0)" ::: "memory");
        __builtin_amdgcn_s_barrier();
    }
    if constexpr (BN == 256) asm volatile("s_waitcnt vmcnt(8)" ::: "memory");
    else                     asm volatile("s_waitcnt vmcnt(6)" ::: "memory");
    __builtin_amdgcn_s_barrier();
    compute((nst - 3) & 3);
    asm volatile("s_waitcnt lgkmcnt(0)" ::: "memory");
    __builtin_amdgcn_s_barrier();
    if constexpr (BN == 256) asm volatile("s_waitcnt vmcnt(4)" ::: "memory");
    else                     asm volatile("s_waitcnt vmcnt(3)" ::: "memory");
    __builtin_amdgcn_s_barrier();
    compute((nst - 2) & 3);
    asm volatile("s_waitcnt lgkmcnt(0)" ::: "memory");
    __builtin_amdgcn_s_barrier();
    asm volatile("s_waitcnt vmcnt(0)" ::: "memory");
    __builtin_amdgcn_s_barrier();
    compute((nst - 1) & 3);

    const int rq = (lane >> 4) * 4;
#pragma unroll
    for (int mt = 0; mt < 8; mt++) {
        int row0 = bm * 256 + wm * 128 + mt * 16 + rq;
#pragma unroll
        for (int n = 0; n < NT; n++) {
            int col = bn * BN + wn * WN + n * 16 + mrow;
            float bvc = (bias && kh == 0) ? bias[col] : 0.f;
#pragma unroll
            for (int r = 0; r < 4; r++) {
                float v = acc[mt][n][r] + bvc;
                if (relu) v = fmaxf(v, 0.f);
                Cb_b[(size_t)(row0 + r) * N + col] = (bf16_t)v;
            }
        }
    }
}

// ---------------------------------------------------------------------------
// 128x256 big-tile GEMM, BK=64, 2-phase dbuf (QK / FF2).  Swizzled LDS.
// Split-K via z: bf16 partial at Cb + kh*M*N (bias only kh==0).
// v11: + T1 XCD chunked swizzle over flattened (x,z) grid.
// ---------------------------------------------------------------------------
template<int BM, int BN>
__global__ __launch_bounds__(512, 2) void gemm_tile(
    const bf16_t* __restrict__ A, const bf16_t* __restrict__ Bt,
    const float* __restrict__ bias, bf16_t* __restrict__ Cb,
    int M, int N, int lda, int Kloc, int relu, int nbn) {
    constexpr int MF = BM / 32;
    constexpr int NT = BN / 64;
    constexpr int WM = BM / 2;
    constexpr int WN = BN / 4;
    __shared__ __attribute__((aligned(16))) bf16_t As[2][2][BM * 32];
    __shared__ __attribute__((aligned(16))) bf16_t Bs[2][2][BN * 32];
    const int tid  = threadIdx.x;
    const int lane = tid & 63;
    const int wave = tid >> 6;
    const int wm = wave >> 2, wn = wave & 3;

    const int nwgx = gridDim.x;
    const int flat = blockIdx.x + nwgx * blockIdx.z;
    const int nwg  = nwgx * gridDim.z;
    const int logical = (flat & 7) * (nwg >> 3) + (flat >> 3);
    const int lx = logical % nwgx;
    const int kh = logical / nwgx;

    const int span  = 8 * nbn;
    const int group = lx / span;
    const int rem   = lx % span;
    const int bm    = group * 8 + (rem & 7);
    const int bn    = rem >> 3;

    bf16_t* Cb_b = Cb + (size_t)kh * M * N;
    const int koff = kh * Kloc;

    const int r4 = tid >> 2;
    const int kcs = ((tid & 3) ^ ((tid >> 3) & 3)) * 8;
    const bf16_t* Ag = A  + (size_t)(bm * BM + r4) * lda + koff + kcs;
    const bf16_t* Bg = Bt + (size_t)(bn * BN + r4) * lda + koff + kcs;

    f32x4 acc[MF][NT] = {};
    const int mrow = lane & 15;
    const int qsw  = (((lane >> 4) ^ ((mrow >> 1) & 3))) * 8;

    auto stage = [&](int kk, int buf) {
#pragma unroll
        for (int hh = 0; hh < 2; hh++) {
#pragma unroll
            for (int i = 0; i < BM / 128; i++)
                gld_lds16(Ag + (size_t)(i * 128) * lda + kk + hh * 32,
                          &As[buf][hh][i * 128 * 32] + tid * 8);
#pragma unroll
            for (int i = 0; i < BN / 128; i++)
                gld_lds16(Bg + (size_t)(i * 128) * lda + kk + hh * 32,
                          &Bs[buf][hh][i * 128 * 32] + tid * 8);
        }
    };

    stage(0, 0);
    __syncthreads();

    const int nsteps = Kloc >> 6;
    for (int st = 0; st < nsteps; ++st) {
        const int cur = st & 1;
        if (st + 1 < nsteps) stage((st + 1) << 6, cur ^ 1);

#pragma unroll
        for (int hh = 0; hh < 2; hh++) {
            bf16x8 bfr[NT];
#pragma unroll
            for (int n = 0; n < NT; n++)
                bfr[n] = *(const bf16x8*)(&Bs[cur][hh][(wn * WN + n * 16 + mrow) * 32 + qsw]);
            __builtin_amdgcn_s_setprio(1);
#pragma unroll
            for (int mt = 0; mt < MF; mt++) {
                bf16x8 af = *(const bf16x8*)(&As[cur][hh][(wm * WM + mt * 16 + mrow) * 32 + qsw]);
#pragma unroll
                for (int n = 0; n < NT; n++)
                    acc[mt][n] = __builtin_amdgcn_mfma_f32_16x16x32_bf16(
                        af, bfr[n], acc[mt][n], 0, 0, 0);
            }
            __builtin_amdgcn_s_setprio(0);
        }
        __syncthreads();
    }

    const int rq = (lane >> 4) * 4;
#pragma unroll
    for (int mt = 0; mt < MF; mt++) {
        int row0 = bm * BM + wm * WM + mt * 16 + rq;
#pragma unroll
        for (int n = 0; n < NT; n++) {
            int col = bn * BN + wn * WN + n * 16 + mrow;
            float bvc = (bias && kh == 0) ? bias[col] : 0.f;
#pragma unroll
            for (int r = 0; r < 4; r++) {
                float v = acc[mt][n][r] + bvc;
                if (relu) v = fmaxf(v, 0.f);
                Cb_b[(size_t)(row0 + r) * N + col] = (bf16_t)v;
            }
        }
    }
}

// ---------------------------------------------------------------------------
// 128^2 GEMM (kept for V-projection: M=1024, row-bias, batched).  Swizzled LDS.
// ---------------------------------------------------------------------------
template<int MT>
__global__ __launch_bounds__(256) void gemm_bt(
    const bf16_t* __restrict__ A, const bf16_t* __restrict__ Bt,
    const float* __restrict__ bias,
    float* __restrict__ Cf, bf16_t* __restrict__ Cb,
    int M, int N, int lda, int Kloc, int relu, int nbn, int bias_row,
    long bt_bstride, long c_bstride) {
    constexpr int TM = MT * 32;
    __shared__ __attribute__((aligned(16))) bf16_t As[2][TM * 32];
    __shared__ __attribute__((aligned(16))) bf16_t Bs[2][128 * 32];
    const int tid  = threadIdx.x;
    const int lane = tid & 63;
    const int wave = tid >> 6;
    const int wm = wave & 1, wn = wave >> 1;
    const int kh = blockIdx.z;

    const int span  = 8 * nbn;
    const int group = blockIdx.x / span;
    const int rem   = blockIdx.x % span;
    const int bm    = group * 8 + (rem & 7);
    const int bn    = rem >> 3;

    const bf16_t* Bt_b = Bt + (size_t)blockIdx.y * bt_bstride;
    float*  Cf_b = Cf ? Cf + (size_t)blockIdx.y * c_bstride + (size_t)kh * M * N : nullptr;
    bf16_t* Cb_b = Cb ? Cb + (size_t)blockIdx.y * c_bstride : nullptr;
    const int koff = kh * Kloc;

    const int r4 = tid >> 2;            // 0..63
    const int kcs = ((tid & 3) ^ ((tid >> 3) & 3)) * 8;
    const bf16_t* Ag = A    + (size_t)(bm * TM  + r4) * lda + koff + kcs;
    const bf16_t* Bg = Bt_b + (size_t)(bn * 128 + r4) * lda + koff + kcs;

    f32x4 acc[MT][4] = {};
    const int mrow = lane & 15;
    const int qsw  = (((lane >> 4) ^ ((mrow >> 1) & 3))) * 8;

    auto stage = [&](int kk, int buf) {
#pragma unroll
        for (int i = 0; i < MT / 2; i++)
            gld_lds16(Ag + (size_t)(i * 64) * lda + kk, &As[buf][i * 64 * 32] + tid * 8);
        gld_lds16(Bg + kk,                        &Bs[buf][0] + tid * 8);
        gld_lds16(Bg + (size_t)64 * lda + kk,     &Bs[buf][64 * 32] + tid * 8);
    };

    stage(0, 0);
    __syncthreads();

    const int nt = Kloc >> 5;
    for (int t7 = 0; t7 < nt; ++t7) {
        const int cur = t7 & 1;
        if (t7 + 1 < nt) stage((t7 + 1) << 5, cur ^ 1);

        bf16x8 af[MT], bfr[4];
#pragma unroll
        for (int mt = 0; mt < MT; mt++)
            af[mt] = *(const bf16x8*)(&As[cur][(wm * (MT * 16) + mt * 16 + mrow) * 32 + qsw]);
#pragma unroll
        for (int nt2 = 0; nt2 < 4; nt2++)
            bfr[nt2] = *(const bf16x8*)(&Bs[cur][(wn * 64 + nt2 * 16 + mrow) * 32 + qsw]);
#pragma unroll
        for (int mt = 0; mt < MT; mt++)
#pragma unroll
            for (int nt2 = 0; nt2 < 4; nt2++)
                acc[mt][nt2] = __builtin_amdgcn_mfma_f32_16x16x32_bf16(
                    af[mt], bfr[nt2], acc[mt][nt2], 0, 0, 0);

        __syncthreads();
    }

    const int rq = (lane >> 4) * 4;
#pragma unroll
    for (int mt = 0; mt < MT; mt++) {
        int row0 = bm * TM + wm * (MT * 16) + mt * 16 + rq;
#pragma unroll
        for (int nt2 = 0; nt2 < 4; nt2++) {
            int col = bn * 128 + wn * 64 + nt2 * 16 + mrow;
            float bvc = (bias && kh == 0 && !bias_row) ? bias[col] : 0.f;
#pragma unroll
            for (int r = 0; r < 4; r++) {
                float bb = (bias && kh == 0 && bias_row) ? bias[row0 + r] : bvc;
                float v = acc[mt][nt2][r] + bb;
                if (relu) v = fmaxf(v, 0.f);
                size_t idx = (size_t)(row0 + r) * N + col;
                if (Cf_b) Cf_b[idx] = v;
                if (Cb_b) Cb_b[idx] = (bf16_t)v;
            }
        }
    }
}

// ---------------------------------------------------------------------------
// MFMA flash attention (bf16, no-max softmax, MFMA row-sum).
// QKb [B*S][2048]: q at h*64, k at 1024+h*64.  Vt [B][1024][2048]: row hd.
// v6 structure (QBLK=128, 8 waves, swizzled K/V, Q pre-scaled).
// v11: + T1 XCD chunked swizzle — each XCD now owns 4 whole heads, so its
// K/V working set (4 x 512KB = 2MB) fits the private L2 instead of every
// head being re-fetched through LLC by blocks on all 8 XCDs.
// ---------------------------------------------------------------------------
__global__ __launch_bounds__(512) void flash_attn_mfma(
    const bf16_t* __restrict__ QKb,
    const bf16_t* __restrict__ Vtg,
    bf16_t* __restrict__ Outb) {
    __shared__ __attribute__((aligned(16))) bf16_t Ks[2][4096];
    __shared__ __attribute__((aligned(16))) bf16_t Vs[2][4096];
    __shared__ __attribute__((aligned(16))) bf16_t Ps[8192];
    const int t = threadIdx.x;                   // 0..511
    const int lane = t & 63, wave = t >> 6;      // 8 waves
    const int g = lane >> 4, cl = lane & 15;

    // T1: flat grid (16,16,2) -> 512 blocks; chunk 64 logical blocks per XCD
    const int flat = blockIdx.x + 16 * blockIdx.y + 256 * blockIdx.z;
    const int logical = (flat & 7) * 64 + (flat >> 3);
    const int q0 = (logical & 15) * 128;
    const int h  = (logical >> 4) & 15;
    const int b  = logical >> 8;

    const int RS = 2048;
    const bf16_t* Qg = QKb + (size_t)(b * 2048 + q0) * RS + h * 64;
    const bf16_t* Kg = QKb + (size_t)(b * 2048) * RS + 1024 + h * 64;
    const bf16_t* Vg = Vtg + ((size_t)b * 1024 + h * 64) * 2048;

    const int sr   = (t >> 2) & 63;
    const int half = t >> 8;
    const int scs  = half * 32 + (((t & 3) ^ ((t >> 3) & 3)) * 8);

    const float C = 0.125f * 1.4426950408889634f;
    const bf16_t* Qrow = Qg + (size_t)(wave * 16 + cl) * RS;
    bf16x8 qr0 = *(const bf16x8*)(Qrow + g * 8);
    bf16x8 qr1 = *(const bf16x8*)(Qrow + 32 + g * 8);
#pragma unroll
    for (int j = 0; j < 8; j++) {
        qr0[j] = (bf16_t)((float)qr0[j] * C);
        qr1[j] = (bf16_t)((float)qr1[j] * C);
    }

    const bf16_t* Kst = Kg + (size_t)sr * RS + scs;
    const bf16_t* Vst = Vg + (size_t)sr * 2048 + scs;

    gld_lds16(Kst, &Ks[0][0] + t * 8);
    gld_lds16(Vst, &Vs[0][0] + t * 8);
    __syncthreads();

    f32x4 Oacc[4] = {};
    f32x4 Lacc = {};
    bf16x8 ones;
#pragma unroll
    for (int j = 0; j < 8; j++) ones[j] = (bf16_t)1.0f;

    const int rowb = wave * 16 + cl;             // P row 0..127
    const int psw  = (cl & 7) << 4;
    const int gsw  = ((g ^ ((cl >> 1) & 3))) * 8;
    char* PsB = (char*)Ps;

    for (int kt_i = 0; kt_i < 32; ++kt_i) {
        const int cur = kt_i & 1;
        if (kt_i + 1 < 32) {
            Kst += (size_t)64 * RS;
            Vst += 64;
            gld_lds16(Kst, &Ks[cur ^ 1][0] + t * 8);
            gld_lds16(Vst, &Vs[cur ^ 1][0] + t * 8);
        }

        f32x4 Sacc[4] = {};
        __builtin_amdgcn_s_setprio(1);
#pragma unroll
        for (int ks = 0; ks < 2; ++ks) {
            bf16x8 bq = ks ? qr1 : qr0;
#pragma unroll
            for (int mt = 0; mt < 4; ++mt) {
                bf16x8 ak = *(const bf16x8*)(&Ks[cur][ks * 2048 + (mt * 16 + cl) * 32 + gsw]);
                Sacc[mt] = __builtin_amdgcn_mfma_f32_16x16x32_bf16(ak, bq, Sacc[mt], 0, 0, 0);
            }
        }
        __builtin_amdgcn_s_setprio(0);

#pragma unroll
        for (int mt = 0; mt < 4; ++mt) {
            bf16x4 p4;
#pragma unroll
            for (int r = 0; r < 4; r++)
                p4[r] = (bf16_t)__builtin_amdgcn_exp2f(Sacc[mt][r]);
            *(bf16x4*)(PsB + ((rowb * 128 + mt * 32 + g * 8) ^ psw)) = p4;
        }

        __builtin_amdgcn_s_setprio(1);
#pragma unroll
        for (int ks = 0; ks < 2; ++ks) {
            bf16x8 ap = *(const bf16x8*)(PsB + ((rowb * 128 + ks * 64 + g * 16) ^ psw));
            Lacc = __builtin_amdgcn_mfma_f32_16x16x32_bf16(ap, ones, Lacc, 0, 0, 0);
#pragma unroll
            for (int nt = 0; nt < 4; ++nt) {
                bf16x8 bv = *(const bf16x8*)(&Vs[cur][ks * 2048 + (nt * 16 + cl) * 32 + gsw]);
                Oacc[nt] = __builtin_amdgcn_mfma_f32_16x16x32_bf16(ap, bv, Oacc[nt], 0, 0, 0);
            }
        }
        __builtin_amdgcn_s_setprio(0);

        __syncthreads();
    }

#pragma unroll
    for (int r = 0; r < 4; r++) {
        float inv = 1.f / Lacc[r];
        int qrow = q0 + wave * 16 + g * 4 + r;
        size_t base = (size_t)(b * 2048 + qrow) * 1024 + h * 64;
#pragma unroll
        for (int nt = 0; nt < 4; nt++)
            Outb[base + nt * 16 + cl] = (bf16_t)(Oacc[nt][r] * inv);
    }
}

// ---------------------------------------------------------------------------
// out = LN(a + Σ_{j<np} p[j]) * g + be ; p = bf16 split-K partials at stride
// pstr.  outb nullable.  one block/row, D=1024.
// ---------------------------------------------------------------------------
__global__ __launch_bounds__(256) void resid_ln4(const float* __restrict__ a,
                                                 const bf16_t* __restrict__ p,
                                                 long pstr, int np,
                                                 const float* __restrict__ g,
                                                 const float* __restrict__ be,
                                                 float* __restrict__ outf,
                                                 bf16_t* __restrict__ outb) {
    const int row = blockIdx.x, t = threadIdx.x;
    const size_t base = (size_t)row * 1024;
    f32x4 v = ((const f32x4*)(a + base))[t];
    for (int j = 0; j < np; j++) {
        bf16x4 pv = ((const bf16x4*)(p + (size_t)j * pstr + base))[t];
        v[0] += (float)pv[0]; v[1] += (float)pv[1];
        v[2] += (float)pv[2]; v[3] += (float)pv[3];
    }
    float sum = v[0] + v[1] + v[2] + v[3];
    float sq  = v[0] * v[0] + v[1] * v[1] + v[2] * v[2] + v[3] * v[3];
#pragma unroll
    for (int o = 1; o < 64; o <<= 1) {
        sum += __shfl_xor(sum, o);
        sq  += __shfl_xor(sq, o);
    }
    __shared__ float red[8];
    int wave = t >> 6, lane = t & 63;
    if (lane == 0) { red[wave] = sum; red[4 + wave] = sq; }
    __syncthreads();
    sum = red[0] + red[1] + red[2] + red[3];
    sq  = red[4] + red[5] + red[6] + red[7];
    float mu  = sum * (1.f / 1024.f);
    float var = sq * (1.f / 1024.f) - mu * mu;
    float rs  = rsqrtf(var + 1e-6f);
    f32x4 g4 = ((const f32x4*)g)[t];
    f32x4 b4 = ((const f32x4*)be)[t];
    f32x4 o = (v - mu) * rs * g4 + b4;
    ((f32x4*)(outf + base))[t] = o;
    if (outb) {
        bf16x4 ob;
        ob[0] = (bf16_t)o[0]; ob[1] = (bf16_t)o[1]; ob[2] = (bf16_t)o[2]; ob[3] = (bf16_t)o[3];
        ((bf16x4*)(outb + base))[t] = ob;
    }
}

// ---------------------------------------------------------------------------
extern "C" void kernel_launch(void* const* d_in, const int* in_sizes, int n_in,
                              void* d_out, int out_size, void* d_ws, size_t ws_size,
                              hipStream_t stream) {
    (void)in_sizes; (void)n_in; (void)out_size; (void)ws_size;
    const float* x   = (const float*)d_in[0];
    const float* wq  = (const float*)d_in[1];
    const float* bq  = (const float*)d_in[2];
    const float* wk  = (const float*)d_in[3];
    const float* bk  = (const float*)d_in[4];
    const float* wv  = (const float*)d_in[5];
    const float* bv  = (const float*)d_in[6];
    const float* wo  = (const float*)d_in[7];
    const float* bo  = (const float*)d_in[8];
    const float* w1  = (const float*)d_in[9];
    const float* b1  = (const float*)d_in[10];
    const float* w2  = (const float*)d_in[11];
    const float* b2  = (const float*)d_in[12];
    const float* g1  = (const float*)d_in[13];
    const float* be1 = (const float*)d_in[14];
    const float* g2  = (const float*)d_in[15];
    const float* be2 = (const float*)d_in[16];
    float* out = (float*)d_out;

    char* ws = (char*)d_ws;
    const size_t MB = 1ull << 20;
    bf16_t* xb    = (bf16_t*)(ws + 0);        //  8MB; reused as ab after V-gemm
    bf16_t* WtQKV = (bf16_t*)(ws + 8 * MB);   //  6MB [q|k|v][1024] rows x 1024
    bf16_t* WtO   = (bf16_t*)(ws + 14 * MB);  //  2MB
    bf16_t* Wt1   = (bf16_t*)(ws + 16 * MB);  //  8MB
    bf16_t* Wt2   = (bf16_t*)(ws + 24 * MB);  //  8MB
    float*  bqkv  = (float*)(ws + 32 * MB);   //  8KB (bq|bk)
    bf16_t* QKb   = (bf16_t*)(ws + 33 * MB);  // 16MB [4096][2048] (dead after attn)
    bf16_t* Vt    = (bf16_t*)(ws + 49 * MB);  //  8MB [2][1024][2048] (dead after attn)
    bf16_t* ffb   = (bf16_t*)(ws + 33 * MB);  // 32MB overlays QKb+Vt
    bf16_t* oab   = (bf16_t*)(ws + 65 * MB);  // 32MB: 4 bf16 partials (dead after LN1)
    bf16_t* f2b   = (bf16_t*)(ws + 65 * MB);  // 16MB: 2 bf16 partials, overlays oab
    float*  hbuf  = (float*)(ws + 97 * MB);   // 16MB
    bf16_t* hb    = (bf16_t*)(ws + 113 * MB); //  8MB
    bf16_t* ab    = xb;
    const long MN = 4096 * 1024;              // partial-buffer stride (elements)

    // 1. prep: transposes (12288 blocks) + cast (4096) + bias pack (1)
    PrepArgs pa;
    pa.w[0] = wq; pa.w[1] = wk; pa.w[2] = wv; pa.w[3] = wo; pa.w[4] = w1; pa.w[5] = w2;
    pa.wt[0] = WtQKV; pa.wt[1] = WtQKV + 1024 * 1024; pa.wt[2] = WtQKV + 2048 * 1024;
    pa.wt[3] = WtO; pa.wt[4] = Wt1; pa.wt[5] = Wt2;
    int Ks[6] = {1024, 1024, 1024, 1024, 1024, 4096};
    int Ns[6] = {1024, 1024, 1024, 1024, 4096, 1024};
    int st[6] = {0, 1024, 2048, 3072, 4096, 8192};
    for (int i = 0; i < 6; i++) { pa.K[i] = Ks[i]; pa.N[i] = Ns[i]; pa.start[i] = st[i]; }
    pa.x = x; pa.xb = xb; pa.castStart = 12288;
    pa.bq = bq; pa.bk = bk; pa.bqkv = bqkv; pa.biasStart = 12288 + 4096;
    prep<<<12288 + 4096 + 1, 256, 0, stream>>>(pa);

    // 2. QK projection -> QKb [4096][2048] bf16  (128x256: 32x8 = 256 blocks)
    gemm_tile<128, 256><<<256, 512, 0, stream>>>(xb, WtQKV, bqkv, QKb,
                                        4096, 2048, 1024, 1024, 0, 8);
    // 3. V projection, transposed output: Vt[b][hd][s] = Wv^T * x_b^T  (128^2 path)
    gemm_bt<2><<<dim3(256, 2, 1), 256, 0, stream>>>(WtQKV + 2048 * 1024, xb, bv,
                                        nullptr, Vt, 1024, 2048, 1024, 1024, 0, 16, 1,
                                        (long)2048 * 1024, (long)1024 * 2048);
    // 4. flash attention -> ab (= xb, dead)   (QBLK=128: 16x16x2 blocks, 512 thr)
    flash_attn_mfma<<<dim3(16, 16, 2), 512, 0, stream>>>(QKb, Vt, ab);
    // 5. Wo projection, split-K=4 -> 4 bf16 partials (deep engine, 64x4 = 256 blk)
    gemm_deep<256><<<dim3(64, 1, 4), 512, 0, stream>>>(ab, WtO, bo, oab,
                                        4096, 1024, 1024, 256, 0, 4);
    // 6. h = LN(x + Σ oab[0..3])
    resid_ln4<<<4096, 256, 0, stream>>>(x, oab, MN, 4, g1, be1, hbuf, hb);
    // 7. FF1 + relu -> ffb bf16   (deep-BK32 256x256: 256 blocks)
    gemm_deep<256><<<256, 512, 0, stream>>>(hb, Wt1, b1, ffb,
                                        4096, 4096, 1024, 1024, 1, 16);
    // 8. FF2 split-K=2 -> 2 bf16 partials (128x256 2-phase: 128 x z2 = 256 blk)
    gemm_tile<128, 256><<<dim3(128, 1, 2), 512, 0, stream>>>(ffb, Wt2, b2, f2b,
                                        4096, 1024, 4096, 2048, 0, 4);
    // 9. out = LN(h + Σ f2b[0..1])
    resid_ln4<<<4096, 256, 0, stream>>>(hbuf, f2b, MN, 2, g2, be2, out, nullptr);
}

// Round 13
// 354.921 us; speedup vs baseline: 1.1783x; 1.0465x over previous
//
#include <hip/hip_runtime.h>
#include <hip/hip_bf16.h>
#include <cmath>

typedef __bf16 bf16_t;
typedef __bf16 bf16x4 __attribute__((ext_vector_type(4)));
typedef __bf16 bf16x8 __attribute__((ext_vector_type(8)));
typedef float  f32x4  __attribute__((ext_vector_type(4)));

// ---------------------------------------------------------------------------
// async global->LDS, 16B per lane (LDS dest = wave-uniform base + lane*16)
// NOTE: each wave stages its own 64-lane slice; vmcnt is PER-WAVE, so any
// cross-wave consumption of staged data needs vmcnt -> s_barrier -> read.
// ---------------------------------------------------------------------------
__device__ __forceinline__ void gld_lds16(const bf16_t* g, bf16_t* l) {
    __builtin_amdgcn_global_load_lds(
        (const __attribute__((address_space(1))) void*)g,
        (__attribute__((address_space(3))) void*)l,
        16, 0, 0);
}

// T1 XCD-aware chunked swizzle (R11-verified: FETCH −33%): logical =
// (flat%8)*(nwg/8) + flat/8, bijective when nwg%8==0 (all grids here).
// LDS bank swizzle (involution, measured 0 conflicts): physical 16B slot =
// logical slot ^ ((row>>1)&3); pre-swizzled global source + XOR'd read.

// ---------------------------------------------------------------------------
// prep: ONE launch for x-cast + 6 weight transposes + qk-bias pack
// ---------------------------------------------------------------------------
struct PrepArgs {
    const float* w[6]; bf16_t* wt[6];
    int K[6], N[6], start[6];
    const float* x; bf16_t* xb; int castStart;   // transpose-region end
    const float* bq; const float* bk; float* bqkv; int biasStart;
};

__global__ __launch_bounds__(256) void prep(PrepArgs pa) {
    __shared__ float tile[32][33];
    const int bid = blockIdx.x, t = threadIdx.x;
    if (bid < pa.castStart) {
        int mi = 0;
#pragma unroll
        for (int i = 1; i < 6; i++) if (bid >= pa.start[i]) mi = i;
        const int tt  = bid - pa.start[mi];
        const int nbx = pa.N[mi] >> 5;
        const int n0 = (tt % nbx) * 32, k0 = (tt / nbx) * 32;
        const float* in = pa.w[mi];
        bf16_t* out = pa.wt[mi];
        const int K = pa.K[mi], N = pa.N[mi];
        const int tx = t & 31, ty = t >> 5;
#pragma unroll
        for (int i = 0; i < 4; i++) {
            int kk = ty + i * 8;
            tile[kk][tx] = in[(size_t)(k0 + kk) * N + n0 + tx];
        }
        __syncthreads();
#pragma unroll
        for (int i = 0; i < 4; i++) {
            int nn = ty + i * 8;
            out[(size_t)(n0 + nn) * K + k0 + tx] = (bf16_t)tile[tx][nn];
        }
    } else if (bid < pa.biasStart) {
        int i = (bid - pa.castStart) * 256 + t;
        f32x4 v = ((const f32x4*)pa.x)[i];
        bf16x4 o;
        o[0] = (bf16_t)v[0]; o[1] = (bf16_t)v[1]; o[2] = (bf16_t)v[2]; o[3] = (bf16_t)v[3];
        ((bf16x4*)pa.xb)[i] = o;
    } else {
#pragma unroll
        for (int j = 0; j < 8; j++) {
            int idx = t * 8 + j;
            pa.bqkv[idx] = idx < 1024 ? pa.bq[idx] : pa.bk[idx - 1024];
        }
    }
}

// ---------------------------------------------------------------------------
// 8-PHASE 256x256 GEMM (m201 port; FF1 / FF2).  BK=64, 2 LDS buffers x 2
// k-halves (128KB), 8 waves (2M x 4N), per-wave 128x64 output.
// Per K-tile: 4 phases (ks = k-half, mg = mt-group), each:
//   {8 ds_read_b128 -> regs; prefetch ONE 16KB half-unit (2 glds); barrier;
//    16 MFMA (setprio); sched_barrier(0); barrier}
// Prefetch map: p0->(t+1,A,h1) p1->(t+1,B,h1) p2->(t+2,A,h0) p3->(t+2,B,h0)
// vmcnt(4) ONCE per tile boundary, then s_barrier + sched_barrier(0)
// *** R12 race fix: vmcnt is per-wave; without the barrier AFTER the vmcnt,
// *** a fast wave could ds_read slices staged by a wave that hadn't passed
// *** its own vmcnt yet (absmax 0.816).  vmcnt -> barrier -> reads.
// Split-K via z: bf16 partial at Cb + kh*M*N (bias only kh==0).  T1 swizzle.
// ---------------------------------------------------------------------------
__global__ __launch_bounds__(512, 1) void gemm_8ph(
    const bf16_t* __restrict__ A, const bf16_t* __restrict__ Bt,
    const float* __restrict__ bias, bf16_t* __restrict__ Cb,
    int M, int N, int lda, int Kloc, int relu, int nbn) {
    __shared__ __attribute__((aligned(16))) bf16_t As[2][2][256 * 32];
    __shared__ __attribute__((aligned(16))) bf16_t Bs[2][2][256 * 32];
    const int tid  = threadIdx.x;            // 0..511
    const int lane = tid & 63;
    const int wave = tid >> 6;               // 0..7
    const int wm = wave >> 2, wn = wave & 3; // 2M x 4N

    // T1 chunked swizzle over flattened (x,z) grid (nwg % 8 == 0)
    const int nwgx = gridDim.x;
    const int flat = blockIdx.x + nwgx * blockIdx.z;
    const int nwg  = nwgx * gridDim.z;
    const int logical = (flat & 7) * (nwg >> 3) + (flat >> 3);
    const int lx = logical % nwgx;
    const int kh = logical / nwgx;

    const int span  = 8 * nbn;
    const int group = lx / span;
    const int rem   = lx % span;
    const int bm    = group * 8 + (rem & 7);
    const int bn    = rem >> 3;

    bf16_t* Cb_b = Cb + (size_t)kh * M * N;
    const int koff = kh * Kloc;

    const int srow   = tid >> 2;             // 0..127
    const int slot_s = ((tid & 3) ^ ((tid >> 3) & 3)) * 8;   // pre-swizzled src
    const bf16_t* Ag = A  + (size_t)(bm * 256 + srow) * lda + koff + slot_s;
    const bf16_t* Bg = Bt + (size_t)(bn * 256 + srow) * lda + koff + slot_s;

    // stage one 16KB half-unit: operand (isB), K-tile T, k-half h -> buf T&1
    auto unit = [&](int T, int isB, int h) {
        const int kk = T * 64 + h * 32;
        if (!isB) {
            gld_lds16(Ag + kk,                     &As[T & 1][h][0]        + tid * 8);
            gld_lds16(Ag + (size_t)128 * lda + kk, &As[T & 1][h][128 * 32] + tid * 8);
        } else {
            gld_lds16(Bg + kk,                     &Bs[T & 1][h][0]        + tid * 8);
            gld_lds16(Bg + (size_t)128 * lda + kk, &Bs[T & 1][h][128 * 32] + tid * 8);
        }
    };

    f32x4 acc[8][4] = {};
    const int mrow = lane & 15;
    const int qsw  = (((lane >> 4) ^ ((mrow >> 1) & 3))) * 8;   // swizzled read

    const int nst = Kloc >> 6;               // K-tiles of 64; >= 2 (16 here)

    // prologue: tile0 complete + tile1 h0 units  (6 units = 12 glds)
    unit(0, 0, 0); unit(0, 1, 0); unit(0, 0, 1); unit(0, 1, 1);
    unit(1, 0, 0); unit(1, 1, 0);

    for (int t = 0; t < nst; ++t) {
        if (t == nst - 1) asm volatile("s_waitcnt vmcnt(0)" ::: "memory");
        else              asm volatile("s_waitcnt vmcnt(4)" ::: "memory");
        __builtin_amdgcn_s_barrier();        // FIX: cross-wave landing guarantee
        __builtin_amdgcn_sched_barrier(0);   // FIX: no ds_read hoist above barrier
        const int buf = t & 1;
#pragma unroll
        for (int p = 0; p < 4; ++p) {
            const int ks = p >> 1, mg = p & 1;
            bf16x8 af[4], bfr[4];
#pragma unroll
            for (int i = 0; i < 4; i++)
                af[i] = *(const bf16x8*)(
                    &As[buf][ks][(wm * 128 + (mg * 4 + i) * 16 + mrow) * 32 + qsw]);
#pragma unroll
            for (int n = 0; n < 4; n++)
                bfr[n] = *(const bf16x8*)(
                    &Bs[buf][ks][(wn * 64 + n * 16 + mrow) * 32 + qsw]);

            if (p == 0)      { if (t + 1 < nst) unit(t + 1, 0, 1); }
            else if (p == 1) { if (t + 1 < nst) unit(t + 1, 1, 1); }
            else if (p == 2) { if (t + 2 < nst) unit(t + 2, 0, 0); }
            else             { if (t + 2 < nst) unit(t + 2, 1, 0); }

            __builtin_amdgcn_s_barrier();
            __builtin_amdgcn_s_setprio(1);
#pragma unroll
            for (int i = 0; i < 4; i++)
#pragma unroll
                for (int n = 0; n < 4; n++)
                    acc[mg * 4 + i][n] = __builtin_amdgcn_mfma_f32_16x16x32_bf16(
                        af[i], bfr[n], acc[mg * 4 + i][n], 0, 0, 0);
            __builtin_amdgcn_s_setprio(0);
            __builtin_amdgcn_sched_barrier(0);   // pin phase's MFMAs+waits here
            __builtin_amdgcn_s_barrier();
        }
    }

    const int rq = (lane >> 4) * 4;
#pragma unroll
    for (int mt = 0; mt < 8; mt++) {
        int row0 = bm * 256 + wm * 128 + mt * 16 + rq;
#pragma unroll
        for (int n = 0; n < 4; n++) {
            int col = bn * 256 + wn * 64 + n * 16 + mrow;
            float bvc = (bias && kh == 0) ? bias[col] : 0.f;
#pragma unroll
            for (int r = 0; r < 4; r++) {
                float v = acc[mt][n][r] + bvc;
                if (relu) v = fmaxf(v, 0.f);
                Cb_b[(size_t)(row0 + r) * N + col] = (bf16_t)v;
            }
        }
    }
}

// ---------------------------------------------------------------------------
// Deep-pipelined 256x256 GEMM (Wo): BK=32, 4 LDS buffers, depth-3 counted
// vmcnt + swizzled LDS + setprio + T1.  [R10-proven on Wo z=4]
// (Safe despite per-wave vmcnt: compute(t) reads are preceded by the barrier
//  pair of step t-1, by which every wave had waited vmcnt for slab t.)
// ---------------------------------------------------------------------------
template<int BN>
__global__ __launch_bounds__(512, 1) void gemm_deep(
    const bf16_t* __restrict__ A, const bf16_t* __restrict__ Bt,
    const float* __restrict__ bias, bf16_t* __restrict__ Cb,
    int M, int N, int lda, int Kloc, int relu, int nbn) {
    constexpr int NT = BN / 64;
    constexpr int WN = BN / 4;
    __shared__ __attribute__((aligned(16))) bf16_t As[4][256 * 32];
    __shared__ __attribute__((aligned(16))) bf16_t Bs[4][BN * 32];
    const int tid  = threadIdx.x;
    const int lane = tid & 63;
    const int wave = tid >> 6;
    const int wm = wave >> 2, wn = wave & 3;

    const int nwgx = gridDim.x;
    const int flat = blockIdx.x + nwgx * blockIdx.z;
    const int nwg  = nwgx * gridDim.z;
    const int logical = (flat & 7) * (nwg >> 3) + (flat >> 3);
    const int lx = logical % nwgx;
    const int kh = logical / nwgx;

    const int span  = 8 * nbn;
    const int group = lx / span;
    const int rem   = lx % span;
    const int bm    = group * 8 + (rem & 7);
    const int bn    = rem >> 3;

    bf16_t* Cb_b = Cb + (size_t)kh * M * N;
    const int koff = kh * Kloc;

    const int srow   = tid >> 2;
    const int slot_s = ((tid & 3) ^ ((tid >> 3) & 3)) * 8;
    const bf16_t* Ag = A  + (size_t)(bm * 256 + srow) * lda + koff + slot_s;
    const bf16_t* Bg = Bt + (size_t)(bn * BN  + srow) * lda + koff + slot_s;

    auto stage = [&](int kk, int buf) {
        gld_lds16(Ag + kk,                       &As[buf][0]        + tid * 8);
        gld_lds16(Ag + (size_t)128 * lda + kk,   &As[buf][128 * 32] + tid * 8);
        gld_lds16(Bg + kk,                       &Bs[buf][0]        + tid * 8);
        if constexpr (BN == 256)
            gld_lds16(Bg + (size_t)128 * lda + kk, &Bs[buf][128 * 32] + tid * 8);
    };

    f32x4 acc[8][NT] = {};
    const int mrow = lane & 15;
    const int qsw  = (((lane >> 4) ^ ((mrow >> 1) & 3))) * 8;

    auto compute = [&](int cur) {
        bf16x8 bfr[NT], af[8];
#pragma unroll
        for (int n = 0; n < NT; n++)
            bfr[n] = *(const bf16x8*)(&Bs[cur][(wn * WN + n * 16 + mrow) * 32 + qsw]);
#pragma unroll
        for (int mt = 0; mt < 8; mt++)
            af[mt] = *(const bf16x8*)(&As[cur][(wm * 128 + mt * 16 + mrow) * 32 + qsw]);
        __builtin_amdgcn_s_setprio(1);
#pragma unroll
        for (int mt = 0; mt < 8; mt++)
#pragma unroll
            for (int n = 0; n < NT; n++)
                acc[mt][n] = __builtin_amdgcn_mfma_f32_16x16x32_bf16(
                    af[mt], bfr[n], acc[mt][n], 0, 0, 0);
        __builtin_amdgcn_s_setprio(0);
    };

    stage(0, 0); stage(32, 1); stage(64, 2);
    const int nst = Kloc >> 5;
    for (int t = 0; t + 3 < nst; ++t) {
        stage((t + 3) * 32, (t + 3) & 3);
        if constexpr (BN == 256) asm volatile("s_waitcnt vmcnt(12)" ::: "memory");
        else                     asm volatile("s_waitcnt vmcnt(9)"  ::: "memory");
        __builtin_amdgcn_s_barrier();
        compute(t & 3);
        asm volatile("s_waitcnt lgkmcnt(0)" ::: "memory");
        __builtin_amdgcn_s_barrier();
    }
    if constexpr (BN == 256) asm volatile("s_waitcnt vmcnt(8)" ::: "memory");
    else                     asm volatile("s_waitcnt vmcnt(6)" ::: "memory");
    __builtin_amdgcn_s_barrier();
    compute((nst - 3) & 3);
    asm volatile("s_waitcnt lgkmcnt(0)" ::: "memory");
    __builtin_amdgcn_s_barrier();
    if constexpr (BN == 256) asm volatile("s_waitcnt vmcnt(4)" ::: "memory");
    else                     asm volatile("s_waitcnt vmcnt(3)" ::: "memory");
    __builtin_amdgcn_s_barrier();
    compute((nst - 2) & 3);
    asm volatile("s_waitcnt lgkmcnt(0)" ::: "memory");
    __builtin_amdgcn_s_barrier();
    asm volatile("s_waitcnt vmcnt(0)" ::: "memory");
    __builtin_amdgcn_s_barrier();
    compute((nst - 1) & 3);

    const int rq = (lane >> 4) * 4;
#pragma unroll
    for (int mt = 0; mt < 8; mt++) {
        int row0 = bm * 256 + wm * 128 + mt * 16 + rq;
#pragma unroll
        for (int n = 0; n < NT; n++) {
            int col = bn * BN + wn * WN + n * 16 + mrow;
            float bvc = (bias && kh == 0) ? bias[col] : 0.f;
#pragma unroll
            for (int r = 0; r < 4; r++) {
                float v = acc[mt][n][r] + bvc;
                if (relu) v = fmaxf(v, 0.f);
                Cb_b[(size_t)(row0 + r) * N + col] = (bf16_t)v;
            }
        }
    }
}

// ---------------------------------------------------------------------------
// 128x256 big-tile GEMM, BK=64, 2-phase dbuf (QK).  Swizzled LDS + T1.
// ---------------------------------------------------------------------------
template<int BM, int BN>
__global__ __launch_bounds__(512, 2) void gemm_tile(
    const bf16_t* __restrict__ A, const bf16_t* __restrict__ Bt,
    const float* __restrict__ bias, bf16_t* __restrict__ Cb,
    int M, int N, int lda, int Kloc, int relu, int nbn) {
    constexpr int MF = BM / 32;
    constexpr int NT = BN / 64;
    constexpr int WM = BM / 2;
    constexpr int WN = BN / 4;
    __shared__ __attribute__((aligned(16))) bf16_t As[2][2][BM * 32];
    __shared__ __attribute__((aligned(16))) bf16_t Bs[2][2][BN * 32];
    const int tid  = threadIdx.x;
    const int lane = tid & 63;
    const int wave = tid >> 6;
    const int wm = wave >> 2, wn = wave & 3;

    const int nwgx = gridDim.x;
    const int flat = blockIdx.x + nwgx * blockIdx.z;
    const int nwg  = nwgx * gridDim.z;
    const int logical = (flat & 7) * (nwg >> 3) + (flat >> 3);
    const int lx = logical % nwgx;
    const int kh = logical / nwgx;

    const int span  = 8 * nbn;
    const int group = lx / span;
    const int rem   = lx % span;
    const int bm    = group * 8 + (rem & 7);
    const int bn    = rem >> 3;

    bf16_t* Cb_b = Cb + (size_t)kh * M * N;
    const int koff = kh * Kloc;

    const int r4 = tid >> 2;
    const int kcs = ((tid & 3) ^ ((tid >> 3) & 3)) * 8;
    const bf16_t* Ag = A  + (size_t)(bm * BM + r4) * lda + koff + kcs;
    const bf16_t* Bg = Bt + (size_t)(bn * BN + r4) * lda + koff + kcs;

    f32x4 acc[MF][NT] = {};
    const int mrow = lane & 15;
    const int qsw  = (((lane >> 4) ^ ((mrow >> 1) & 3))) * 8;

    auto stage = [&](int kk, int buf) {
#pragma unroll
        for (int hh = 0; hh < 2; hh++) {
#pragma unroll
            for (int i = 0; i < BM / 128; i++)
                gld_lds16(Ag + (size_t)(i * 128) * lda + kk + hh * 32,
                          &As[buf][hh][i * 128 * 32] + tid * 8);
#pragma unroll
            for (int i = 0; i < BN / 128; i++)
                gld_lds16(Bg + (size_t)(i * 128) * lda + kk + hh * 32,
                          &Bs[buf][hh][i * 128 * 32] + tid * 8);
        }
    };

    stage(0, 0);
    __syncthreads();

    const int nsteps = Kloc >> 6;
    for (int st = 0; st < nsteps; ++st) {
        const int cur = st & 1;
        if (st + 1 < nsteps) stage((st + 1) << 6, cur ^ 1);

#pragma unroll
        for (int hh = 0; hh < 2; hh++) {
            bf16x8 bfr[NT];
#pragma unroll
            for (int n = 0; n < NT; n++)
                bfr[n] = *(const bf16x8*)(&Bs[cur][hh][(wn * WN + n * 16 + mrow) * 32 + qsw]);
            __builtin_amdgcn_s_setprio(1);
#pragma unroll
            for (int mt = 0; mt < MF; mt++) {
                bf16x8 af = *(const bf16x8*)(&As[cur][hh][(wm * WM + mt * 16 + mrow) * 32 + qsw]);
#pragma unroll
                for (int n = 0; n < NT; n++)
                    acc[mt][n] = __builtin_amdgcn_mfma_f32_16x16x32_bf16(
                        af, bfr[n], acc[mt][n], 0, 0, 0);
            }
            __builtin_amdgcn_s_setprio(0);
        }
        __syncthreads();
    }

    const int rq = (lane >> 4) * 4;
#pragma unroll
    for (int mt = 0; mt < MF; mt++) {
        int row0 = bm * BM + wm * WM + mt * 16 + rq;
#pragma unroll
        for (int n = 0; n < NT; n++) {
            int col = bn * BN + wn * WN + n * 16 + mrow;
            float bvc = (bias && kh == 0) ? bias[col] : 0.f;
#pragma unroll
            for (int r = 0; r < 4; r++) {
                float v = acc[mt][n][r] + bvc;
                if (relu) v = fmaxf(v, 0.f);
                Cb_b[(size_t)(row0 + r) * N + col] = (bf16_t)v;
            }
        }
    }
}

// ---------------------------------------------------------------------------
// 128^2 GEMM (kept for V-projection: M=1024, row-bias, batched).  Swizzled LDS.
// ---------------------------------------------------------------------------
template<int MT>
__global__ __launch_bounds__(256) void gemm_bt(
    const bf16_t* __restrict__ A, const bf16_t* __restrict__ Bt,
    const float* __restrict__ bias,
    float* __restrict__ Cf, bf16_t* __restrict__ Cb,
    int M, int N, int lda, int Kloc, int relu, int nbn, int bias_row,
    long bt_bstride, long c_bstride) {
    constexpr int TM = MT * 32;
    __shared__ __attribute__((aligned(16))) bf16_t As[2][TM * 32];
    __shared__ __attribute__((aligned(16))) bf16_t Bs[2][128 * 32];
    const int tid  = threadIdx.x;
    const int lane = tid & 63;
    const int wave = tid >> 6;
    const int wm = wave & 1, wn = wave >> 1;
    const int kh = blockIdx.z;

    const int span  = 8 * nbn;
    const int group = blockIdx.x / span;
    const int rem   = blockIdx.x % span;
    const int bm    = group * 8 + (rem & 7);
    const int bn    = rem >> 3;

    const bf16_t* Bt_b = Bt + (size_t)blockIdx.y * bt_bstride;
    float*  Cf_b = Cf ? Cf + (size_t)blockIdx.y * c_bstride + (size_t)kh * M * N : nullptr;
    bf16_t* Cb_b = Cb ? Cb + (size_t)blockIdx.y * c_bstride : nullptr;
    const int koff = kh * Kloc;

    const int r4 = tid >> 2;            // 0..63
    const int kcs = ((tid & 3) ^ ((tid >> 3) & 3)) * 8;
    const bf16_t* Ag = A    + (size_t)(bm * TM  + r4) * lda + koff + kcs;
    const bf16_t* Bg = Bt_b + (size_t)(bn * 128 + r4) * lda + koff + kcs;

    f32x4 acc[MT][4] = {};
    const int mrow = lane & 15;
    const int qsw  = (((lane >> 4) ^ ((mrow >> 1) & 3))) * 8;

    auto stage = [&](int kk, int buf) {
#pragma unroll
        for (int i = 0; i < MT / 2; i++)
            gld_lds16(Ag + (size_t)(i * 64) * lda + kk, &As[buf][i * 64 * 32] + tid * 8);
        gld_lds16(Bg + kk,                        &Bs[buf][0] + tid * 8);
        gld_lds16(Bg + (size_t)64 * lda + kk,     &Bs[buf][64 * 32] + tid * 8);
    };

    stage(0, 0);
    __syncthreads();

    const int nt = Kloc >> 5;
    for (int t7 = 0; t7 < nt; ++t7) {
        const int cur = t7 & 1;
        if (t7 + 1 < nt) stage((t7 + 1) << 5, cur ^ 1);

        bf16x8 af[MT], bfr[4];
#pragma unroll
        for (int mt = 0; mt < MT; mt++)
            af[mt] = *(const bf16x8*)(&As[cur][(wm * (MT * 16) + mt * 16 + mrow) * 32 + qsw]);
#pragma unroll
        for (int nt2 = 0; nt2 < 4; nt2++)
            bfr[nt2] = *(const bf16x8*)(&Bs[cur][(wn * 64 + nt2 * 16 + mrow) * 32 + qsw]);
#pragma unroll
        for (int mt = 0; mt < MT; mt++)
#pragma unroll
            for (int nt2 = 0; nt2 < 4; nt2++)
                acc[mt][nt2] = __builtin_amdgcn_mfma_f32_16x16x32_bf16(
                    af[mt], bfr[nt2], acc[mt][nt2], 0, 0, 0);

        __syncthreads();
    }

    const int rq = (lane >> 4) * 4;
#pragma unroll
    for (int mt = 0; mt < MT; mt++) {
        int row0 = bm * TM + wm * (MT * 16) + mt * 16 + rq;
#pragma unroll
        for (int nt2 = 0; nt2 < 4; nt2++) {
            int col = bn * 128 + wn * 64 + nt2 * 16 + mrow;
            float bvc = (bias && kh == 0 && !bias_row) ? bias[col] : 0.f;
#pragma unroll
            for (int r = 0; r < 4; r++) {
                float bb = (bias && kh == 0 && bias_row) ? bias[row0 + r] : bvc;
                float v = acc[mt][nt2][r] + bb;
                if (relu) v = fmaxf(v, 0.f);
                size_t idx = (size_t)(row0 + r) * N + col;
                if (Cf_b) Cf_b[idx] = v;
                if (Cb_b) Cb_b[idx] = (bf16_t)v;
            }
        }
    }
}

// ---------------------------------------------------------------------------
// MFMA flash attention (bf16, no-max softmax, MFMA row-sum).
// QKb [B*S][2048]: q at h*64, k at 1024+h*64.  Vt [B][1024][2048]: row hd.
// QBLK=128, 8 waves, swizzled K/V, Q pre-scaled, T1 head-chunking.
// ---------------------------------------------------------------------------
__global__ __launch_bounds__(512) void flash_attn_mfma(
    const bf16_t* __restrict__ QKb,
    const bf16_t* __restrict__ Vtg,
    bf16_t* __restrict__ Outb) {
    __shared__ __attribute__((aligned(16))) bf16_t Ks[2][4096];
    __shared__ __attribute__((aligned(16))) bf16_t Vs[2][4096];
    __shared__ __attribute__((aligned(16))) bf16_t Ps[8192];
    const int t = threadIdx.x;                   // 0..511
    const int lane = t & 63, wave = t >> 6;      // 8 waves
    const int g = lane >> 4, cl = lane & 15;

    const int flat = blockIdx.x + 16 * blockIdx.y + 256 * blockIdx.z;
    const int logical = (flat & 7) * 64 + (flat >> 3);
    const int q0 = (logical & 15) * 128;
    const int h  = (logical >> 4) & 15;
    const int b  = logical >> 8;

    const int RS = 2048;
    const bf16_t* Qg = QKb + (size_t)(b * 2048 + q0) * RS + h * 64;
    const bf16_t* Kg = QKb + (size_t)(b * 2048) * RS + 1024 + h * 64;
    const bf16_t* Vg = Vtg + ((size_t)b * 1024 + h * 64) * 2048;

    const int sr   = (t >> 2) & 63;
    const int half = t >> 8;
    const int scs  = half * 32 + (((t & 3) ^ ((t >> 3) & 3)) * 8);

    const float C = 0.125f * 1.4426950408889634f;
    const bf16_t* Qrow = Qg + (size_t)(wave * 16 + cl) * RS;
    bf16x8 qr0 = *(const bf16x8*)(Qrow + g * 8);
    bf16x8 qr1 = *(const bf16x8*)(Qrow + 32 + g * 8);
#pragma unroll
    for (int j = 0; j < 8; j++) {
        qr0[j] = (bf16_t)((float)qr0[j] * C);
        qr1[j] = (bf16_t)((float)qr1[j] * C);
    }

    const bf16_t* Kst = Kg + (size_t)sr * RS + scs;
    const bf16_t* Vst = Vg + (size_t)sr * 2048 + scs;

    gld_lds16(Kst, &Ks[0][0] + t * 8);
    gld_lds16(Vst, &Vs[0][0] + t * 8);
    __syncthreads();

    f32x4 Oacc[4] = {};
    f32x4 Lacc = {};
    bf16x8 ones;
#pragma unroll
    for (int j = 0; j < 8; j++) ones[j] = (bf16_t)1.0f;

    const int rowb = wave * 16 + cl;             // P row 0..127
    const int psw  = (cl & 7) << 4;
    const int gsw  = ((g ^ ((cl >> 1) & 3))) * 8;
    char* PsB = (char*)Ps;

    for (int kt_i = 0; kt_i < 32; ++kt_i) {
        const int cur = kt_i & 1;
        if (kt_i + 1 < 32) {
            Kst += (size_t)64 * RS;
            Vst += 64;
            gld_lds16(Kst, &Ks[cur ^ 1][0] + t * 8);
            gld_lds16(Vst, &Vs[cur ^ 1][0] + t * 8);
        }

        f32x4 Sacc[4] = {};
        __builtin_amdgcn_s_setprio(1);
#pragma unroll
        for (int ks = 0; ks < 2; ++ks) {
            bf16x8 bq = ks ? qr1 : qr0;
#pragma unroll
            for (int mt = 0; mt < 4; ++mt) {
                bf16x8 ak = *(const bf16x8*)(&Ks[cur][ks * 2048 + (mt * 16 + cl) * 32 + gsw]);
                Sacc[mt] = __builtin_amdgcn_mfma_f32_16x16x32_bf16(ak, bq, Sacc[mt], 0, 0, 0);
            }
        }
        __builtin_amdgcn_s_setprio(0);

#pragma unroll
        for (int mt = 0; mt < 4; ++mt) {
            bf16x4 p4;
#pragma unroll
            for (int r = 0; r < 4; r++)
                p4[r] = (bf16_t)__builtin_amdgcn_exp2f(Sacc[mt][r]);
            *(bf16x4*)(PsB + ((rowb * 128 + mt * 32 + g * 8) ^ psw)) = p4;
        }

        __builtin_amdgcn_s_setprio(1);
#pragma unroll
        for (int ks = 0; ks < 2; ++ks) {
            bf16x8 ap = *(const bf16x8*)(PsB + ((rowb * 128 + ks * 64 + g * 16) ^ psw));
            Lacc = __builtin_amdgcn_mfma_f32_16x16x32_bf16(ap, ones, Lacc, 0, 0, 0);
#pragma unroll
            for (int nt = 0; nt < 4; ++nt) {
                bf16x8 bv = *(const bf16x8*)(&Vs[cur][ks * 2048 + (nt * 16 + cl) * 32 + gsw]);
                Oacc[nt] = __builtin_amdgcn_mfma_f32_16x16x32_bf16(ap, bv, Oacc[nt], 0, 0, 0);
            }
        }
        __builtin_amdgcn_s_setprio(0);

        __syncthreads();
    }

#pragma unroll
    for (int r = 0; r < 4; r++) {
        float inv = 1.f / Lacc[r];
        int qrow = q0 + wave * 16 + g * 4 + r;
        size_t base = (size_t)(b * 2048 + qrow) * 1024 + h * 64;
#pragma unroll
        for (int nt = 0; nt < 4; nt++)
            Outb[base + nt * 16 + cl] = (bf16_t)(Oacc[nt][r] * inv);
    }
}

// ---------------------------------------------------------------------------
// out = LN(a + Σ_{j<np} p[j]) * g + be ; p = bf16 split-K partials at stride
// pstr.  outb nullable.  one block/row, D=1024.
// ---------------------------------------------------------------------------
__global__ __launch_bounds__(256) void resid_ln4(const float* __restrict__ a,
                                                 const bf16_t* __restrict__ p,
                                                 long pstr, int np,
                                                 const float* __restrict__ g,
                                                 const float* __restrict__ be,
                                                 float* __restrict__ outf,
                                                 bf16_t* __restrict__ outb) {
    const int row = blockIdx.x, t = threadIdx.x;
    const size_t base = (size_t)row * 1024;
    f32x4 v = ((const f32x4*)(a + base))[t];
    for (int j = 0; j < np; j++) {
        bf16x4 pv = ((const bf16x4*)(p + (size_t)j * pstr + base))[t];
        v[0] += (float)pv[0]; v[1] += (float)pv[1];
        v[2] += (float)pv[2]; v[3] += (float)pv[3];
    }
    float sum = v[0] + v[1] + v[2] + v[3];
    float sq  = v[0] * v[0] + v[1] * v[1] + v[2] * v[2] + v[3] * v[3];
#pragma unroll
    for (int o = 1; o < 64; o <<= 1) {
        sum += __shfl_xor(sum, o);
        sq  += __shfl_xor(sq, o);
    }
    __shared__ float red[8];
    int wave = t >> 6, lane = t & 63;
    if (lane == 0) { red[wave] = sum; red[4 + wave] = sq; }
    __syncthreads();
    sum = red[0] + red[1] + red[2] + red[3];
    sq  = red[4] + red[5] + red[6] + red[7];
    float mu  = sum * (1.f / 1024.f);
    float var = sq * (1.f / 1024.f) - mu * mu;
    float rs  = rsqrtf(var + 1e-6f);
    f32x4 g4 = ((const f32x4*)g)[t];
    f32x4 b4 = ((const f32x4*)be)[t];
    f32x4 o = (v - mu) * rs * g4 + b4;
    ((f32x4*)(outf + base))[t] = o;
    if (outb) {
        bf16x4 ob;
        ob[0] = (bf16_t)o[0]; ob[1] = (bf16_t)o[1]; ob[2] = (bf16_t)o[2]; ob[3] = (bf16_t)o[3];
        ((bf16x4*)(outb + base))[t] = ob;
    }
}

// ---------------------------------------------------------------------------
extern "C" void kernel_launch(void* const* d_in, const int* in_sizes, int n_in,
                              void* d_out, int out_size, void* d_ws, size_t ws_size,
                              hipStream_t stream) {
    (void)in_sizes; (void)n_in; (void)out_size; (void)ws_size;
    const float* x   = (const float*)d_in[0];
    const float* wq  = (const float*)d_in[1];
    const float* bq  = (const float*)d_in[2];
    const float* wk  = (const float*)d_in[3];
    const float* bk  = (const float*)d_in[4];
    const float* wv  = (const float*)d_in[5];
    const float* bv  = (const float*)d_in[6];
    const float* wo  = (const float*)d_in[7];
    const float* bo  = (const float*)d_in[8];
    const float* w1  = (const float*)d_in[9];
    const float* b1  = (const float*)d_in[10];
    const float* w2  = (const float*)d_in[11];
    const float* b2  = (const float*)d_in[12];
    const float* g1  = (const float*)d_in[13];
    const float* be1 = (const float*)d_in[14];
    const float* g2  = (const float*)d_in[15];
    const float* be2 = (const float*)d_in[16];
    float* out = (float*)d_out;

    char* ws = (char*)d_ws;
    const size_t MB = 1ull << 20;
    bf16_t* xb    = (bf16_t*)(ws + 0);        //  8MB; reused as ab after V-gemm
    bf16_t* WtQKV = (bf16_t*)(ws + 8 * MB);   //  6MB [q|k|v][1024] rows x 1024
    bf16_t* WtO   = (bf16_t*)(ws + 14 * MB);  //  2MB
    bf16_t* Wt1   = (bf16_t*)(ws + 16 * MB);  //  8MB
    bf16_t* Wt2   = (bf16_t*)(ws + 24 * MB);  //  8MB
    float*  bqkv  = (float*)(ws + 32 * MB);   //  8KB (bq|bk)
    bf16_t* QKb   = (bf16_t*)(ws + 33 * MB);  // 16MB [4096][2048] (dead after attn)
    bf16_t* Vt    = (bf16_t*)(ws + 49 * MB);  //  8MB [2][1024][2048] (dead after attn)
    bf16_t* ffb   = (bf16_t*)(ws + 33 * MB);  // 32MB overlays QKb+Vt
    bf16_t* oab   = (bf16_t*)(ws + 65 * MB);  // 32MB: 4 bf16 partials (dead after LN1)
    bf16_t* f2b   = (bf16_t*)(ws + 65 * MB);  // 32MB: 4 bf16 partials, overlays oab
    float*  hbuf  = (float*)(ws + 97 * MB);   // 16MB
    bf16_t* hb    = (bf16_t*)(ws + 113 * MB); //  8MB
    bf16_t* ab    = xb;
    const long MN = 4096 * 1024;              // partial-buffer stride (elements)

    // 1. prep: transposes (12288 blocks) + cast (4096) + bias pack (1)
    PrepArgs pa;
    pa.w[0] = wq; pa.w[1] = wk; pa.w[2] = wv; pa.w[3] = wo; pa.w[4] = w1; pa.w[5] = w2;
    pa.wt[0] = WtQKV; pa.wt[1] = WtQKV + 1024 * 1024; pa.wt[2] = WtQKV + 2048 * 1024;
    pa.wt[3] = WtO; pa.wt[4] = Wt1; pa.wt[5] = Wt2;
    int Ks[6] = {1024, 1024, 1024, 1024, 1024, 4096};
    int Ns[6] = {1024, 1024, 1024, 1024, 4096, 1024};
    int st[6] = {0, 1024, 2048, 3072, 4096, 8192};
    for (int i = 0; i < 6; i++) { pa.K[i] = Ks[i]; pa.N[i] = Ns[i]; pa.start[i] = st[i]; }
    pa.x = x; pa.xb = xb; pa.castStart = 12288;
    pa.bq = bq; pa.bk = bk; pa.bqkv = bqkv; pa.biasStart = 12288 + 4096;
    prep<<<12288 + 4096 + 1, 256, 0, stream>>>(pa);

    // 2. QK projection -> QKb [4096][2048] bf16  (128x256 2-phase: 256 blocks)
    gemm_tile<128, 256><<<256, 512, 0, stream>>>(xb, WtQKV, bqkv, QKb,
                                        4096, 2048, 1024, 1024, 0, 8);
    // 3. V projection, transposed output: Vt[b][hd][s] = Wv^T * x_b^T  (128^2 path)
    gemm_bt<2><<<dim3(256, 2, 1), 256, 0, stream>>>(WtQKV + 2048 * 1024, xb, bv,
                                        nullptr, Vt, 1024, 2048, 1024, 1024, 0, 16, 1,
                                        (long)2048 * 1024, (long)1024 * 2048);
    // 4. flash attention -> ab (= xb, dead)   (QBLK=128: 16x16x2 blocks, 512 thr)
    flash_attn_mfma<<<dim3(16, 16, 2), 512, 0, stream>>>(QKb, Vt, ab);
    // 5. Wo projection, split-K=4 -> 4 bf16 partials (deep engine, 64x4 = 256 blk)
    gemm_deep<256><<<dim3(64, 1, 4), 512, 0, stream>>>(ab, WtO, bo, oab,
                                        4096, 1024, 1024, 256, 0, 4);
    // 6. h = LN(x + Σ oab[0..3])
    resid_ln4<<<4096, 256, 0, stream>>>(x, oab, MN, 4, g1, be1, hbuf, hb);
    // 7. FF1 + relu -> ffb bf16   (8-PHASE engine, race-fixed: 256 blocks)
    gemm_8ph<<<256, 512, 0, stream>>>(hb, Wt1, b1, ffb,
                                        4096, 4096, 1024, 1024, 1, 16);
    // 8. FF2 split-K=4 -> 4 bf16 partials (8-PHASE, race-fixed: 64 x z4 = 256)
    gemm_8ph<<<dim3(64, 1, 4), 512, 0, stream>>>(ffb, Wt2, b2, f2b,
                                        4096, 1024, 4096, 1024, 0, 4);
    // 9. out = LN(h + Σ f2b[0..3])
    resid_ln4<<<4096, 256, 0, stream>>>(hbuf, f2b, MN, 4, g2, be2, out, nullptr);
}